// Round 1
// baseline (1016.528 us; speedup 1.0000x reference)
//
#include <hip/hip_runtime.h>
#include <hip/hip_bf16.h>

#define S_LEN 2048
#define BATCH 4
#define EMB   512
#define NH    8
#define HD    64
#define SB    (S_LEN*BATCH)   // 8192
#define E3    (3*EMB)         // 1536

// ---------------------------------------------------------------------------
// Kernel 1: qkv = query @ W_in^T + b_in   (M=8192, N=1536, K=512)
// scatter into q/k/v laid out as (B, H, S, HD)
// ---------------------------------------------------------------------------
__global__ __launch_bounds__(256) void k_qkv(const float* __restrict__ Q,
    const float* __restrict__ W, const float* __restrict__ bin,
    float* __restrict__ qw, float* __restrict__ kw, float* __restrict__ vw)
{
    __shared__ float As[16][68];
    __shared__ float Bs[16][68];
    const int row0 = blockIdx.x * 64;
    const int col0 = blockIdx.y * 64;
    const int tid = threadIdx.x;
    const int tm = tid & 15, tn = tid >> 4;
    const int lr = tid >> 2;          // 0..63
    const int lk = (tid & 3) * 4;     // 0,4,8,12

    float acc[4][4] = {};
    for (int k0 = 0; k0 < EMB; k0 += 16) {
        float4 a = *(const float4*)&Q[(size_t)(row0 + lr) * EMB + k0 + lk];
        float4 b = *(const float4*)&W[(size_t)(col0 + lr) * EMB + k0 + lk];
        __syncthreads();
        As[lk+0][lr] = a.x; As[lk+1][lr] = a.y; As[lk+2][lr] = a.z; As[lk+3][lr] = a.w;
        Bs[lk+0][lr] = b.x; Bs[lk+1][lr] = b.y; Bs[lk+2][lr] = b.z; Bs[lk+3][lr] = b.w;
        __syncthreads();
        #pragma unroll
        for (int kk = 0; kk < 16; ++kk) {
            float4 av = *(const float4*)&As[kk][tm*4];
            float4 bv = *(const float4*)&Bs[kk][tn*4];
            float aa[4] = {av.x, av.y, av.z, av.w};
            float bb[4] = {bv.x, bv.y, bv.z, bv.w};
            #pragma unroll
            for (int i = 0; i < 4; ++i)
                #pragma unroll
                for (int j = 0; j < 4; ++j)
                    acc[i][j] = fmaf(aa[i], bb[j], acc[i][j]);
        }
    }
    // scatter: r = row0+tm*4+i -> s = row0/4 + tm (B=4), b = i
    const int which = col0 >> 9;               // 0:q 1:k 2:v (64 | 512 boundaries)
    const int h     = (col0 & 511) >> 6;       // constant per block
    const int dn    = tn * 4;
    float* dst = (which == 0) ? qw : (which == 1) ? kw : vw;
    const int s = (row0 >> 2) + tm;
    #pragma unroll
    for (int i = 0; i < 4; ++i) {
        const int b = i;
        float4 o4;
        o4.x = acc[i][0] + bin[col0 + dn + 0];
        o4.y = acc[i][1] + bin[col0 + dn + 1];
        o4.z = acc[i][2] + bin[col0 + dn + 2];
        o4.w = acc[i][3] + bin[col0 + dn + 3];
        *(float4*)&dst[(((size_t)b*NH + h)*S_LEN + s)*HD + dn] = o4;
    }
}

// ---------------------------------------------------------------------------
// Kernel 2: scores(b,h) = clip( (q @ k^T)*scale + clip(bias,±5)*0.05 , ±30 )
// writes pre-softmax scores into the attn region of d_out
// ---------------------------------------------------------------------------
__global__ __launch_bounds__(256) void k_scores(const float* __restrict__ qw,
    const float* __restrict__ kw, const float* __restrict__ rpb,
    float* __restrict__ att)
{
    __shared__ float qs[64][68];   // [d][m]
    __shared__ float ks[64][68];   // [d][n]
    const int bh   = blockIdx.z;
    const int row0 = blockIdx.x * 64;
    const int col0 = blockIdx.y * 64;
    const int h    = bh & (NH - 1);
    const int tid  = threadIdx.x;
    const int tm = tid & 15, tn = tid >> 4;

    const float* qb = qw + ((size_t)bh * S_LEN + row0) * HD;
    const float* kb = kw + ((size_t)bh * S_LEN + col0) * HD;
    #pragma unroll
    for (int t = 0; t < 4; ++t) {
        int idx = tid + t * 256;      // 0..1023
        int m  = idx >> 4;            // 0..63
        int d4 = (idx & 15) * 4;
        float4 a = *(const float4*)&qb[(size_t)m * HD + d4];
        float4 b = *(const float4*)&kb[(size_t)m * HD + d4];
        qs[d4+0][m]=a.x; qs[d4+1][m]=a.y; qs[d4+2][m]=a.z; qs[d4+3][m]=a.w;
        ks[d4+0][m]=b.x; ks[d4+1][m]=b.y; ks[d4+2][m]=b.z; ks[d4+3][m]=b.w;
    }
    __syncthreads();

    float acc[4][4] = {};
    #pragma unroll 8
    for (int kk = 0; kk < 64; ++kk) {
        float4 av = *(const float4*)&qs[kk][tm*4];
        float4 bv = *(const float4*)&ks[kk][tn*4];
        float aa[4] = {av.x, av.y, av.z, av.w};
        float bb[4] = {bv.x, bv.y, bv.z, bv.w};
        #pragma unroll
        for (int i = 0; i < 4; ++i)
            #pragma unroll
            for (int j = 0; j < 4; ++j)
                acc[i][j] = fmaf(aa[i], bb[j], acc[i][j]);
    }

    const float scale = 0.125f;   // 1/sqrt(64)
    #pragma unroll
    for (int i = 0; i < 4; ++i) {
        const int qi = row0 + tm*4 + i;
        const size_t bidx = (size_t)h*S_LEN*S_LEN + (size_t)qi*S_LEN + col0 + tn*4;
        float4 bv = *(const float4*)&rpb[bidx];
        float bb[4] = {bv.x, bv.y, bv.z, bv.w};
        float4 o4;
        float* po = (float*)&o4;
        #pragma unroll
        for (int j = 0; j < 4; ++j) {
            float bc = fminf(fmaxf(bb[j], -5.f), 5.f) * 0.05f;
            float v  = acc[i][j] * scale + bc;
            po[j] = fminf(fmaxf(v, -30.f), 30.f);
        }
        *(float4*)&att[(size_t)bh*S_LEN*S_LEN + (size_t)qi*S_LEN + col0 + tn*4] = o4;
    }
}

// ---------------------------------------------------------------------------
// Kernel 3: fused row softmax (in place on attn region). One block per row.
// ---------------------------------------------------------------------------
__global__ __launch_bounds__(256) void k_softmax(float* __restrict__ att)
{
    __shared__ float red_m[4];
    __shared__ float red_l[4];
    const size_t row = blockIdx.x;
    float* p = att + row * S_LEN;
    const int tid = threadIdx.x;

    float4 x0 = *(const float4*)&p[tid * 4];
    float4 x1 = *(const float4*)&p[1024 + tid * 4];
    float x[8] = {x0.x, x0.y, x0.z, x0.w, x1.x, x1.y, x1.z, x1.w};

    float m = x[0];
    #pragma unroll
    for (int i = 1; i < 8; ++i) m = fmaxf(m, x[i]);
    #pragma unroll
    for (int off = 32; off > 0; off >>= 1) m = fmaxf(m, __shfl_xor(m, off));
    const int wid = tid >> 6, lane = tid & 63;
    if (lane == 0) red_m[wid] = m;
    __syncthreads();
    m = fmaxf(fmaxf(red_m[0], red_m[1]), fmaxf(red_m[2], red_m[3]));

    float e[8];
    float l = 0.f;
    #pragma unroll
    for (int i = 0; i < 8; ++i) { e[i] = expf(x[i] - m); l += e[i]; }
    #pragma unroll
    for (int off = 32; off > 0; off >>= 1) l += __shfl_xor(l, off);
    if (lane == 0) red_l[wid] = l;
    __syncthreads();
    l = red_l[0] + red_l[1] + red_l[2] + red_l[3];
    const float inv = 1.0f / l;

    float4 w0, w1;
    w0.x = e[0]*inv; w0.y = e[1]*inv; w0.z = e[2]*inv; w0.w = e[3]*inv;
    w1.x = e[4]*inv; w1.y = e[5]*inv; w1.z = e[6]*inv; w1.w = e[7]*inv;
    *(float4*)&p[tid * 4] = w0;
    *(float4*)&p[1024 + tid * 4] = w1;
}

// ---------------------------------------------------------------------------
// Kernel 4: ctx = attn @ v  per (b,h); ctx laid out (S*B, E), clipped ±10
// ---------------------------------------------------------------------------
__global__ __launch_bounds__(256) void k_pv(const float* __restrict__ att,
    const float* __restrict__ vw, float* __restrict__ ctx)
{
    __shared__ float Ws[16][68];   // [kk][m]
    __shared__ float Vs[16][68];   // [kk][n]
    const int bh   = blockIdx.z;
    const int row0 = blockIdx.x * 64;
    const int tid  = threadIdx.x;
    const int tm = tid & 15, tn = tid >> 4;
    const int lr = tid >> 2;          // 0..63
    const int lk = (tid & 3) * 4;     // 0,4,8,12
    const int kv = tid >> 4;          // 0..15
    const int n4 = (tid & 15) * 4;

    const float* ab = att + (size_t)bh * S_LEN * S_LEN;
    const float* vb = vw  + (size_t)bh * S_LEN * HD;

    float acc[4][4] = {};
    for (int k0 = 0; k0 < S_LEN; k0 += 16) {
        float4 a = *(const float4*)&ab[(size_t)(row0 + lr) * S_LEN + k0 + lk];
        float4 b = *(const float4*)&vb[(size_t)(k0 + kv) * HD + n4];
        __syncthreads();
        Ws[lk+0][lr] = a.x; Ws[lk+1][lr] = a.y; Ws[lk+2][lr] = a.z; Ws[lk+3][lr] = a.w;
        *(float4*)&Vs[kv][n4] = b;
        __syncthreads();
        #pragma unroll
        for (int kk = 0; kk < 16; ++kk) {
            float4 av = *(const float4*)&Ws[kk][tm*4];
            float4 bv = *(const float4*)&Vs[kk][tn*4];
            float aa[4] = {av.x, av.y, av.z, av.w};
            float bb[4] = {bv.x, bv.y, bv.z, bv.w};
            #pragma unroll
            for (int i = 0; i < 4; ++i)
                #pragma unroll
                for (int j = 0; j < 4; ++j)
                    acc[i][j] = fmaf(aa[i], bb[j], acc[i][j]);
        }
    }
    const int b = bh >> 3, h = bh & 7;
    #pragma unroll
    for (int i = 0; i < 4; ++i) {
        const int sq = row0 + tm*4 + i;
        float4 o4;
        o4.x = fminf(fmaxf(acc[i][0], -10.f), 10.f);
        o4.y = fminf(fmaxf(acc[i][1], -10.f), 10.f);
        o4.z = fminf(fmaxf(acc[i][2], -10.f), 10.f);
        o4.w = fminf(fmaxf(acc[i][3], -10.f), 10.f);
        *(float4*)&ctx[((size_t)sq*BATCH + b)*EMB + h*HD + tn*4] = o4;
    }
}

// ---------------------------------------------------------------------------
// Kernel 5: out = ctx @ W_out^T + b_out   (M=8192, N=512, K=512) -> d_out (S,B,E)
// ---------------------------------------------------------------------------
__global__ __launch_bounds__(256) void k_outproj(const float* __restrict__ C,
    const float* __restrict__ W, const float* __restrict__ bout,
    float* __restrict__ out)
{
    __shared__ float As[16][68];
    __shared__ float Bs[16][68];
    const int row0 = blockIdx.x * 64;
    const int col0 = blockIdx.y * 64;
    const int tid = threadIdx.x;
    const int tm = tid & 15, tn = tid >> 4;
    const int lr = tid >> 2;
    const int lk = (tid & 3) * 4;

    float acc[4][4] = {};
    for (int k0 = 0; k0 < EMB; k0 += 16) {
        float4 a = *(const float4*)&C[(size_t)(row0 + lr) * EMB + k0 + lk];
        float4 b = *(const float4*)&W[(size_t)(col0 + lr) * EMB + k0 + lk];
        __syncthreads();
        As[lk+0][lr] = a.x; As[lk+1][lr] = a.y; As[lk+2][lr] = a.z; As[lk+3][lr] = a.w;
        Bs[lk+0][lr] = b.x; Bs[lk+1][lr] = b.y; Bs[lk+2][lr] = b.z; Bs[lk+3][lr] = b.w;
        __syncthreads();
        #pragma unroll
        for (int kk = 0; kk < 16; ++kk) {
            float4 av = *(const float4*)&As[kk][tm*4];
            float4 bv = *(const float4*)&Bs[kk][tn*4];
            float aa[4] = {av.x, av.y, av.z, av.w};
            float bb[4] = {bv.x, bv.y, bv.z, bv.w};
            #pragma unroll
            for (int i = 0; i < 4; ++i)
                #pragma unroll
                for (int j = 0; j < 4; ++j)
                    acc[i][j] = fmaf(aa[i], bb[j], acc[i][j]);
        }
    }
    #pragma unroll
    for (int i = 0; i < 4; ++i) {
        const int r = row0 + tm*4 + i;
        float4 o4;
        o4.x = acc[i][0] + bout[col0 + tn*4 + 0];
        o4.y = acc[i][1] + bout[col0 + tn*4 + 1];
        o4.z = acc[i][2] + bout[col0 + tn*4 + 2];
        o4.w = acc[i][3] + bout[col0 + tn*4 + 3];
        *(float4*)&out[(size_t)r * EMB + col0 + tn*4] = o4;
    }
}

// ---------------------------------------------------------------------------
extern "C" void kernel_launch(void* const* d_in, const int* in_sizes, int n_in,
                              void* d_out, int out_size, void* d_ws, size_t ws_size,
                              hipStream_t stream) {
    const float* query = (const float*)d_in[0];
    // d_in[1] (key) and d_in[2] (value) are unused: reference projects qkv
    // all from `query` (replicating the torch in_proj-on-q behavior).
    const float* rpb  = (const float*)d_in[3];
    const float* Win  = (const float*)d_in[4];
    const float* bin  = (const float*)d_in[5];
    const float* Wout = (const float*)d_in[6];
    const float* bout = (const float*)d_in[7];

    float* out = (float*)d_out;
    float* att = out + (size_t)S_LEN * BATCH * EMB;   // (B,H,S,S)

    float* ws = (float*)d_ws;
    const size_t per = (size_t)BATCH * NH * S_LEN * HD;   // 4.19M floats
    float* qw  = ws;
    float* kw  = qw + per;
    float* vw  = kw + per;
    float* ctx = vw + per;

    k_qkv<<<dim3(SB/64, E3/64), 256, 0, stream>>>(query, Win, bin, qw, kw, vw);
    k_scores<<<dim3(S_LEN/64, S_LEN/64, BATCH*NH), 256, 0, stream>>>(qw, kw, rpb, att);
    k_softmax<<<dim3(BATCH*NH*S_LEN), 256, 0, stream>>>(att);
    k_pv<<<dim3(S_LEN/64, 1, BATCH*NH), 256, 0, stream>>>(att, vw, ctx);
    k_outproj<<<dim3(SB/64, EMB/64), 256, 0, stream>>>(ctx, Wout, bout, out);
}

// Round 2
// 811.365 us; speedup vs baseline: 1.2529x; 1.2529x over previous
//
#include <hip/hip_runtime.h>
#include <hip/hip_bf16.h>

#define S_LEN 2048
#define BATCH 4
#define EMB   512
#define NH    8
#define HD    64
#define SB    (S_LEN*BATCH)   // 8192
#define E3    (3*EMB)         // 1536
#define BH    (BATCH*NH)      // 32

typedef _Float16 f16;
typedef _Float16 f16x4 __attribute__((ext_vector_type(4)));
typedef _Float16 f16x8 __attribute__((ext_vector_type(8)));
typedef float    f32x4 __attribute__((ext_vector_type(4)));

// ---------------------------------------------------------------------------
// Kernel 1: qkv = query @ W_in^T + b_in  (fp32 SIMD GEMM, proven in round 0)
// epilogue now writes fp16: Qh,Kh as (bh, s, d); V transposed -> Vt (bh, d, s)
// ---------------------------------------------------------------------------
__global__ __launch_bounds__(256) void k_qkv(const float* __restrict__ Q,
    const float* __restrict__ W, const float* __restrict__ bin,
    f16* __restrict__ Qh, f16* __restrict__ Kh, f16* __restrict__ Vt)
{
    __shared__ float As[16][68];
    __shared__ float Bs[16][68];
    const int row0 = blockIdx.x * 64;
    const int col0 = blockIdx.y * 64;
    const int tid = threadIdx.x;
    const int tm = tid & 15, tn = tid >> 4;
    const int lr = tid >> 2;          // 0..63
    const int lk = (tid & 3) * 4;     // 0,4,8,12

    float acc[4][4] = {};
    for (int k0 = 0; k0 < EMB; k0 += 16) {
        float4 a = *(const float4*)&Q[(size_t)(row0 + lr) * EMB + k0 + lk];
        float4 b = *(const float4*)&W[(size_t)(col0 + lr) * EMB + k0 + lk];
        __syncthreads();
        As[lk+0][lr] = a.x; As[lk+1][lr] = a.y; As[lk+2][lr] = a.z; As[lk+3][lr] = a.w;
        Bs[lk+0][lr] = b.x; Bs[lk+1][lr] = b.y; Bs[lk+2][lr] = b.z; Bs[lk+3][lr] = b.w;
        __syncthreads();
        #pragma unroll
        for (int kk = 0; kk < 16; ++kk) {
            float4 av = *(const float4*)&As[kk][tm*4];
            float4 bv = *(const float4*)&Bs[kk][tn*4];
            float aa[4] = {av.x, av.y, av.z, av.w};
            float bb[4] = {bv.x, bv.y, bv.z, bv.w};
            #pragma unroll
            for (int i = 0; i < 4; ++i)
                #pragma unroll
                for (int j = 0; j < 4; ++j)
                    acc[i][j] = fmaf(aa[i], bb[j], acc[i][j]);
        }
    }
    const int which = col0 >> 9;               // 0:q 1:k 2:v
    const int h     = (col0 & 511) >> 6;
    const int dn    = tn * 4;                  // head-dim base (0..60)
    const int s     = (row0 >> 2) + tm;        // seq index
    #pragma unroll
    for (int i = 0; i < 4; ++i) {
        const int b  = i;                      // batch index
        const int bh = b * NH + h;
        float v0 = acc[i][0] + bin[col0 + dn + 0];
        float v1 = acc[i][1] + bin[col0 + dn + 1];
        float v2 = acc[i][2] + bin[col0 + dn + 2];
        float v3 = acc[i][3] + bin[col0 + dn + 3];
        if (which == 2) {
            f16* vt = Vt + ((size_t)bh * HD + dn) * S_LEN + s;
            vt[0 * S_LEN] = (f16)v0;
            vt[1 * S_LEN] = (f16)v1;
            vt[2 * S_LEN] = (f16)v2;
            vt[3 * S_LEN] = (f16)v3;
        } else {
            f16* dst = (which == 0 ? Qh : Kh) + ((size_t)bh * S_LEN + s) * HD + dn;
            f16x4 o;
            o[0] = (f16)v0; o[1] = (f16)v1; o[2] = (f16)v2; o[3] = (f16)v3;
            *(f16x4*)dst = o;
        }
    }
}

// ---------------------------------------------------------------------------
// Kernel 2: fused scores+softmax+PV. One block = (bh, 64 q-rows); 4 waves x 16 rows.
// Pass 1: S = QK^T*scale + clip(bias)*0.05, clip +-30; accumulate l = sum exp(S-30).
// Pass 2: recompute S, w = exp(S-30)/l -> write attn fp32; LDS-transpose w->fp16
//         A-frags; O += P.V via MFMA (V consumed d-major from Vt). ctx = clip(O,+-10).
// Softmax shift of 30 == reference softmax (shift invariant; fp32 never underflows).
// ---------------------------------------------------------------------------
__global__ __launch_bounds__(256) void k_attn(
    const f16* __restrict__ Qh, const f16* __restrict__ Kh, const f16* __restrict__ Vt,
    const float* __restrict__ rpb, float* __restrict__ att, float* __restrict__ ctx)
{
    __shared__ f16 Pw[4][16][64];   // per-wave P-transpose tile (XOR-swizzled)
    const int tid = threadIdx.x;
    const int w  = tid >> 6;
    const int l  = tid & 63;
    const int g  = l >> 4;          // lane group 0..3
    const int li = l & 15;          // lane-in-group
    const int bh = blockIdx.y;
    const int h  = bh & (NH - 1);
    const int b  = bh >> 3;
    const int r0 = blockIdx.x * 64 + w * 16;   // this wave's q-row base

    // Q fragments (A): row = li, k = kb*32 + g*8 + j (consistent k-convention)
    const f16* qbase = Qh + ((size_t)bh * S_LEN + r0 + li) * HD;
    const f16x8 aq0 = *(const f16x8*)(qbase + g * 8);
    const f16x8 aq1 = *(const f16x8*)(qbase + 32 + g * 8);

    const f16*   kbase = Kh  + (size_t)bh * S_LEN * HD;
    const f16*   vtb   = Vt  + (size_t)bh * HD * S_LEN;
    const float* bias  = rpb + (size_t)h * S_LEN * S_LEN;
    float*       attb  = att + (size_t)bh * S_LEN * S_LEN;

    const f32x4 zero = {0.f, 0.f, 0.f, 0.f};
    float ls[4] = {0.f, 0.f, 0.f, 0.f};

    // ---------------- PASS 1: row sums ----------------
    for (int t = 0; t < 32; ++t) {
        const int c0 = t * 64;
        f32x4 s[4];
        #pragma unroll
        for (int n = 0; n < 4; ++n) {
            const f16* kp = kbase + (size_t)(c0 + n*16 + li) * HD + g * 8;
            f16x8 b0 = *(const f16x8*)kp;
            f16x8 b1 = *(const f16x8*)(kp + 32);
            f32x4 acc = __builtin_amdgcn_mfma_f32_16x16x32_f16(aq0, b0, zero, 0, 0, 0);
            s[n] = __builtin_amdgcn_mfma_f32_16x16x32_f16(aq1, b1, acc, 0, 0, 0);
        }
        #pragma unroll
        for (int n = 0; n < 4; ++n) {
            const int col = c0 + n*16 + li;
            #pragma unroll
            for (int jj = 0; jj < 4; ++jj) {
                const int row = r0 + g*4 + jj;
                float bb = bias[(size_t)row * S_LEN + col];
                bb = fminf(fmaxf(bb, -5.f), 5.f) * 0.05f;
                float v = s[n][jj] * 0.125f + bb;
                v = fminf(fmaxf(v, -30.f), 30.f);
                ls[jj] += __expf(v - 30.f);
            }
        }
    }
    // reduce row sums across the 16 lanes sharing each row group
    #pragma unroll
    for (int jj = 0; jj < 4; ++jj) {
        #pragma unroll
        for (int m = 1; m < 16; m <<= 1)
            ls[jj] += __shfl_xor(ls[jj], m);
    }
    float inv[4];
    #pragma unroll
    for (int jj = 0; jj < 4; ++jj) inv[jj] = 1.0f / ls[jj];

    // ---------------- PASS 2: write weights + PV ----------------
    f32x4 o[4];
    #pragma unroll
    for (int n = 0; n < 4; ++n) o[n] = zero;
    f16* pw = &Pw[w][0][0];

    for (int t = 0; t < 32; ++t) {
        const int c0 = t * 64;
        f32x4 s[4];
        #pragma unroll
        for (int n = 0; n < 4; ++n) {
            const f16* kp = kbase + (size_t)(c0 + n*16 + li) * HD + g * 8;
            f16x8 b0 = *(const f16x8*)kp;
            f16x8 b1 = *(const f16x8*)(kp + 32);
            f32x4 acc = __builtin_amdgcn_mfma_f32_16x16x32_f16(aq0, b0, zero, 0, 0, 0);
            s[n] = __builtin_amdgcn_mfma_f32_16x16x32_f16(aq1, b1, acc, 0, 0, 0);
        }
        #pragma unroll
        for (int n = 0; n < 4; ++n) {
            const int col  = c0 + n*16 + li;
            const int colL = n*16 + li;            // in-tile col 0..63
            const int cb   = colL >> 3;            // 16B chunk index 0..7
            #pragma unroll
            for (int jj = 0; jj < 4; ++jj) {
                const int row = r0 + g*4 + jj;
                float bb = bias[(size_t)row * S_LEN + col];
                bb = fminf(fmaxf(bb, -5.f), 5.f) * 0.05f;
                float v = s[n][jj] * 0.125f + bb;
                v = fminf(fmaxf(v, -30.f), 30.f);
                float e  = __expf(v - 30.f);
                float wt = e * inv[jj];
                attb[(size_t)row * S_LEN + col] = wt;       // normalized weight fp32
                const int r16 = g*4 + jj;
                // XOR-swizzled LDS write (16B-chunk granularity) for conflict-free read
                pw[r16*64 + (((cb) ^ (r16 & 7)) << 3) + (colL & 7)] = (f16)wt;
            }
        }
        // read P A-frags: row = li, k = kb*32 + g*8 + j (same convention as write)
        f16x8 pa0 = *(const f16x8*)(pw + li*64 + (((g    ) ^ (li & 7)) << 3));
        f16x8 pa1 = *(const f16x8*)(pw + li*64 + (((4 + g) ^ (li & 7)) << 3));
        #pragma unroll
        for (int n = 0; n < 4; ++n) {
            const f16* vp = vtb + (size_t)(n*16 + li) * S_LEN + c0 + g * 8;
            f16x8 v0 = *(const f16x8*)vp;
            f16x8 v1 = *(const f16x8*)(vp + 32);
            o[n] = __builtin_amdgcn_mfma_f32_16x16x32_f16(pa0, v0, o[n], 0, 0, 0);
            o[n] = __builtin_amdgcn_mfma_f32_16x16x32_f16(pa1, v1, o[n], 0, 0, 0);
        }
    }

    // epilogue: ctx[(s*B + b)*E + h*64 + d], clipped +-10
    #pragma unroll
    for (int n = 0; n < 4; ++n) {
        #pragma unroll
        for (int jj = 0; jj < 4; ++jj) {
            const int row = r0 + g*4 + jj;
            float v = fminf(fmaxf(o[n][jj], -10.f), 10.f);
            ctx[((size_t)row * BATCH + b) * EMB + h * HD + n*16 + li] = v;
        }
    }
}

// ---------------------------------------------------------------------------
// Kernel 3: out = ctx @ W_out^T + b_out  (fp32 SIMD GEMM, proven in round 0)
// ---------------------------------------------------------------------------
__global__ __launch_bounds__(256) void k_outproj(const float* __restrict__ C,
    const float* __restrict__ W, const float* __restrict__ bout,
    float* __restrict__ out)
{
    __shared__ float As[16][68];
    __shared__ float Bs[16][68];
    const int row0 = blockIdx.x * 64;
    const int col0 = blockIdx.y * 64;
    const int tid = threadIdx.x;
    const int tm = tid & 15, tn = tid >> 4;
    const int lr = tid >> 2;
    const int lk = (tid & 3) * 4;

    float acc[4][4] = {};
    for (int k0 = 0; k0 < EMB; k0 += 16) {
        float4 a = *(const float4*)&C[(size_t)(row0 + lr) * EMB + k0 + lk];
        float4 b = *(const float4*)&W[(size_t)(col0 + lr) * EMB + k0 + lk];
        __syncthreads();
        As[lk+0][lr] = a.x; As[lk+1][lr] = a.y; As[lk+2][lr] = a.z; As[lk+3][lr] = a.w;
        Bs[lk+0][lr] = b.x; Bs[lk+1][lr] = b.y; Bs[lk+2][lr] = b.z; Bs[lk+3][lr] = b.w;
        __syncthreads();
        #pragma unroll
        for (int kk = 0; kk < 16; ++kk) {
            float4 av = *(const float4*)&As[kk][tm*4];
            float4 bv = *(const float4*)&Bs[kk][tn*4];
            float aa[4] = {av.x, av.y, av.z, av.w};
            float bb[4] = {bv.x, bv.y, bv.z, bv.w};
            #pragma unroll
            for (int i = 0; i < 4; ++i)
                #pragma unroll
                for (int j = 0; j < 4; ++j)
                    acc[i][j] = fmaf(aa[i], bb[j], acc[i][j]);
        }
    }
    #pragma unroll
    for (int i = 0; i < 4; ++i) {
        const int r = row0 + tm*4 + i;
        float4 o4;
        o4.x = acc[i][0] + bout[col0 + tn*4 + 0];
        o4.y = acc[i][1] + bout[col0 + tn*4 + 1];
        o4.z = acc[i][2] + bout[col0 + tn*4 + 2];
        o4.w = acc[i][3] + bout[col0 + tn*4 + 3];
        *(float4*)&out[(size_t)r * EMB + col0 + tn*4] = o4;
    }
}

// ---------------------------------------------------------------------------
extern "C" void kernel_launch(void* const* d_in, const int* in_sizes, int n_in,
                              void* d_out, int out_size, void* d_ws, size_t ws_size,
                              hipStream_t stream) {
    const float* query = (const float*)d_in[0];
    // d_in[1], d_in[2] unused: reference projects q,k,v all from `query`.
    const float* rpb  = (const float*)d_in[3];
    const float* Win  = (const float*)d_in[4];
    const float* bin  = (const float*)d_in[5];
    const float* Wout = (const float*)d_in[6];
    const float* bout = (const float*)d_in[7];

    float* out = (float*)d_out;
    float* att = out + (size_t)S_LEN * BATCH * EMB;   // (B,H,S,S) fp32

    const size_t per = (size_t)BH * S_LEN * HD;       // 4,194,304 elements
    f16*   Qh  = (f16*)d_ws;
    f16*   Kh  = Qh + per;
    f16*   Vt  = Kh + per;
    float* ctx = (float*)(Vt + per);                  // fp32 (SB, E)

    k_qkv   <<<dim3(SB/64, E3/64),        256, 0, stream>>>(query, Win, bin, Qh, Kh, Vt);
    k_attn  <<<dim3(S_LEN/64, BH),        256, 0, stream>>>(Qh, Kh, Vt, rpb, att, ctx);
    k_outproj<<<dim3(SB/64, EMB/64),      256, 0, stream>>>(ctx, Wout, bout, out);
}

// Round 4
// 702.204 us; speedup vs baseline: 1.4476x; 1.1555x over previous
//
#include <hip/hip_runtime.h>
#include <hip/hip_bf16.h>

#define S_LEN 2048
#define BATCH 4
#define EMB   512
#define NH    8
#define HD    64
#define SB    (S_LEN*BATCH)   // 8192
#define E3    (3*EMB)         // 1536
#define BH    (BATCH*NH)      // 32

typedef _Float16 f16;
typedef _Float16 f16x4 __attribute__((ext_vector_type(4)));
typedef _Float16 f16x8 __attribute__((ext_vector_type(8)));
typedef float    f32x4 __attribute__((ext_vector_type(4)));

// ---------------------------------------------------------------------------
// Kernel 1: qkv = query @ W_in^T + b_in  (fp32 SIMD GEMM, proven)
// writes fp16: Qh,Kh as (bh, s, d); V transposed -> Vt (bh, d, s)
// ---------------------------------------------------------------------------
__global__ __launch_bounds__(256) void k_qkv(const float* __restrict__ Q,
    const float* __restrict__ W, const float* __restrict__ bin,
    f16* __restrict__ Qh, f16* __restrict__ Kh, f16* __restrict__ Vt)
{
    __shared__ float As[16][68];
    __shared__ float Bs[16][68];
    const int row0 = blockIdx.x * 64;
    const int col0 = blockIdx.y * 64;
    const int tid = threadIdx.x;
    const int tm = tid & 15, tn = tid >> 4;
    const int lr = tid >> 2;          // 0..63
    const int lk = (tid & 3) * 4;     // 0,4,8,12

    float acc[4][4] = {};
    for (int k0 = 0; k0 < EMB; k0 += 16) {
        float4 a = *(const float4*)&Q[(size_t)(row0 + lr) * EMB + k0 + lk];
        float4 b = *(const float4*)&W[(size_t)(col0 + lr) * EMB + k0 + lk];
        __syncthreads();
        As[lk+0][lr] = a.x; As[lk+1][lr] = a.y; As[lk+2][lr] = a.z; As[lk+3][lr] = a.w;
        Bs[lk+0][lr] = b.x; Bs[lk+1][lr] = b.y; Bs[lk+2][lr] = b.z; Bs[lk+3][lr] = b.w;
        __syncthreads();
        #pragma unroll
        for (int kk = 0; kk < 16; ++kk) {
            float4 av = *(const float4*)&As[kk][tm*4];
            float4 bv = *(const float4*)&Bs[kk][tn*4];
            float aa[4] = {av.x, av.y, av.z, av.w};
            float bb[4] = {bv.x, bv.y, bv.z, bv.w};
            #pragma unroll
            for (int i = 0; i < 4; ++i)
                #pragma unroll
                for (int j = 0; j < 4; ++j)
                    acc[i][j] = fmaf(aa[i], bb[j], acc[i][j]);
        }
    }
    const int which = col0 >> 9;               // 0:q 1:k 2:v
    const int h     = (col0 & 511) >> 6;
    const int dn    = tn * 4;                  // head-dim base (0..60)
    const int s     = (row0 >> 2) + tm;        // seq index
    #pragma unroll
    for (int i = 0; i < 4; ++i) {
        const int b  = i;                      // batch index
        const int bh = b * NH + h;
        float v0 = acc[i][0] + bin[col0 + dn + 0];
        float v1 = acc[i][1] + bin[col0 + dn + 1];
        float v2 = acc[i][2] + bin[col0 + dn + 2];
        float v3 = acc[i][3] + bin[col0 + dn + 3];
        if (which == 2) {
            f16* vt = Vt + ((size_t)bh * HD + dn) * S_LEN + s;
            vt[0 * S_LEN] = (f16)v0;
            vt[1 * S_LEN] = (f16)v1;
            vt[2 * S_LEN] = (f16)v2;
            vt[3 * S_LEN] = (f16)v3;
        } else {
            f16* dst = (which == 0 ? Qh : Kh) + ((size_t)bh * S_LEN + s) * HD + dn;
            f16x4 o;
            o[0] = (f16)v0; o[1] = (f16)v1; o[2] = (f16)v2; o[3] = (f16)v3;
            *(f16x4*)dst = o;
        }
    }
}

// ---------------------------------------------------------------------------
// Kernel 2: fused scores+softmax+PV, TRANSPOSED score layout.
// S^T tile = mfma(A=K_frag, B=Q_frag): lane owns q-row (li) and 4 consecutive
// k-cols per acc reg -> float4 bias loads, float4 nt att stores, per-lane
// scalar row-sum. P -> LDS [q][k] (16B-XOR swizzle) -> b128 A-frags for PV.
// Fixed softmax shift of 30 (scores clipped to ±30) == reference softmax.
// ---------------------------------------------------------------------------
__global__ __launch_bounds__(256) void k_attn(
    const f16* __restrict__ Qh, const f16* __restrict__ Kh, const f16* __restrict__ Vt,
    const float* __restrict__ rpb, float* __restrict__ att, float* __restrict__ ctx)
{
    __shared__ f16 Pw[4][1024];     // per-wave 16(q) x 64(k) f16, 16B-chunk XOR swizzle
    const int tid = threadIdx.x;
    const int w  = tid >> 6;
    const int l  = tid & 63;
    const int g  = l >> 4;          // lane group 0..3
    const int li = l & 15;          // lane-in-group = this lane's q-row
    const int bh = blockIdx.y;
    const int h  = bh & (NH - 1);
    const int b  = bh >> 3;
    const int r0 = blockIdx.x * 64 + w * 16;   // wave's q-row base
    const int row_l = r0 + li;                 // this lane's q-row

    // Q fragment (B-operand): B[k=g*8+j][col=li] = Q[row_l][k]
    const f16* qbase = Qh + ((size_t)bh * S_LEN + row_l) * HD;
    const f16x8 bq0 = *(const f16x8*)(qbase + g * 8);
    const f16x8 bq1 = *(const f16x8*)(qbase + 32 + g * 8);

    const f16*   kbase = Kh  + (size_t)bh * S_LEN * HD;
    const f16*   vtb   = Vt  + (size_t)bh * HD * S_LEN;
    const float* brow  = rpb + ((size_t)h * S_LEN + row_l) * S_LEN;   // lane's bias row
    float*       arow  = att + ((size_t)bh * S_LEN + row_l) * S_LEN;  // lane's att row

    const f32x4 zero = {0.f, 0.f, 0.f, 0.f};
    float ls = 0.f;

    // ---------------- PASS 1: per-row sums of exp(S-30) ----------------
    for (int t = 0; t < 32; ++t) {
        const int c0 = t * 64;
        #pragma unroll
        for (int n = 0; n < 4; ++n) {
            const f16* kp = kbase + (size_t)(c0 + n*16 + li) * HD + g * 8;
            f16x8 ak0 = *(const f16x8*)kp;
            f16x8 ak1 = *(const f16x8*)(kp + 32);
            f32x4 bv = *(const f32x4*)&brow[c0 + n*16 + g*4];
            f32x4 st = __builtin_amdgcn_mfma_f32_16x16x32_f16(ak0, bq0, zero, 0, 0, 0);
            st = __builtin_amdgcn_mfma_f32_16x16x32_f16(ak1, bq1, st, 0, 0, 0);
            #pragma unroll
            for (int jj = 0; jj < 4; ++jj) {
                float bc = fminf(fmaxf(bv[jj], -5.f), 5.f) * 0.05f;
                float v  = st[jj] * 0.125f + bc;
                v = fminf(fmaxf(v, -30.f), 30.f);
                ls += __expf(v - 30.f);
            }
        }
    }
    // reduce across the 4 lanes (g=0..3) sharing this q-row
    ls += __shfl_xor(ls, 16);
    ls += __shfl_xor(ls, 32);
    const float inv = 1.0f / ls;

    // ---------------- PASS 2: normalized weights + PV ----------------
    f32x4 o[4];
    #pragma unroll
    for (int n = 0; n < 4; ++n) o[n] = zero;
    f16* pw = &Pw[w][0];

    for (int t = 0; t < 32; ++t) {
        const int c0 = t * 64;
        #pragma unroll
        for (int n = 0; n < 4; ++n) {
            const f16* kp = kbase + (size_t)(c0 + n*16 + li) * HD + g * 8;
            f16x8 ak0 = *(const f16x8*)kp;
            f16x8 ak1 = *(const f16x8*)(kp + 32);
            f32x4 bv = *(const f32x4*)&brow[c0 + n*16 + g*4];
            f32x4 st = __builtin_amdgcn_mfma_f32_16x16x32_f16(ak0, bq0, zero, 0, 0, 0);
            st = __builtin_amdgcn_mfma_f32_16x16x32_f16(ak1, bq1, st, 0, 0, 0);
            f32x4 w4;
            f16x4 p4;
            #pragma unroll
            for (int jj = 0; jj < 4; ++jj) {
                float bc = fminf(fmaxf(bv[jj], -5.f), 5.f) * 0.05f;
                float v  = st[jj] * 0.125f + bc;
                v = fminf(fmaxf(v, -30.f), 30.f);
                float wt = __expf(v - 30.f) * inv;
                w4[jj] = wt;
                p4[jj] = (f16)wt;
            }
            // normalized weights -> att (nontemporal: keep LLC for bias)
            __builtin_nontemporal_store(w4, (f32x4*)&arow[c0 + n*16 + g*4]);
            // P^T -> LDS [q=li][k=n*16+g*4..+3], 16B-chunk XOR swizzle
            const int pc = ((n*2 + (g >> 1)) ^ li) & 7;   // phys 16B chunk (0..7)
            *(f16x4*)(pw + li*64 + pc*8 + (g & 1)*4) = p4;
        }
        // PV: O = mfma(A=P, B=V^T-frag). A-frag: row=li, k=g*8+j (b128 reads)
        f16x8 pa0 = *(const f16x8*)(pw + li*64 + ((g ^ li) & 7) * 8);
        f16x8 pa1 = *(const f16x8*)(pw + li*64 + (((4 + g) ^ li) & 7) * 8);
        #pragma unroll
        for (int n = 0; n < 4; ++n) {
            const f16* vp = vtb + (size_t)(n*16 + li) * S_LEN + c0 + g * 8;
            f16x8 v0 = *(const f16x8*)vp;
            f16x8 v1 = *(const f16x8*)(vp + 32);
            o[n] = __builtin_amdgcn_mfma_f32_16x16x32_f16(pa0, v0, o[n], 0, 0, 0);
            o[n] = __builtin_amdgcn_mfma_f32_16x16x32_f16(pa1, v1, o[n], 0, 0, 0);
        }
    }

    // epilogue: ctx[(s*B + b)*E + h*64 + d], clipped ±10
    #pragma unroll
    for (int n = 0; n < 4; ++n) {
        #pragma unroll
        for (int jj = 0; jj < 4; ++jj) {
            const int row = r0 + g*4 + jj;
            float v = fminf(fmaxf(o[n][jj], -10.f), 10.f);
            ctx[((size_t)row * BATCH + b) * EMB + h * HD + n*16 + li] = v;
        }
    }
}

// ---------------------------------------------------------------------------
// Kernel 3: out = ctx @ W_out^T + b_out  (fp32 SIMD GEMM, proven)
// ---------------------------------------------------------------------------
__global__ __launch_bounds__(256) void k_outproj(const float* __restrict__ C,
    const float* __restrict__ W, const float* __restrict__ bout,
    float* __restrict__ out)
{
    __shared__ float As[16][68];
    __shared__ float Bs[16][68];
    const int row0 = blockIdx.x * 64;
    const int col0 = blockIdx.y * 64;
    const int tid = threadIdx.x;
    const int tm = tid & 15, tn = tid >> 4;
    const int lr = tid >> 2;
    const int lk = (tid & 3) * 4;

    float acc[4][4] = {};
    for (int k0 = 0; k0 < EMB; k0 += 16) {
        float4 a = *(const float4*)&C[(size_t)(row0 + lr) * EMB + k0 + lk];
        float4 b = *(const float4*)&W[(size_t)(col0 + lr) * EMB + k0 + lk];
        __syncthreads();
        As[lk+0][lr] = a.x; As[lk+1][lr] = a.y; As[lk+2][lr] = a.z; As[lk+3][lr] = a.w;
        Bs[lk+0][lr] = b.x; Bs[lk+1][lr] = b.y; Bs[lk+2][lr] = b.z; Bs[lk+3][lr] = b.w;
        __syncthreads();
        #pragma unroll
        for (int kk = 0; kk < 16; ++kk) {
            float4 av = *(const float4*)&As[kk][tm*4];
            float4 bv = *(const float4*)&Bs[kk][tn*4];
            float aa[4] = {av.x, av.y, av.z, av.w};
            float bb[4] = {bv.x, bv.y, bv.z, bv.w};
            #pragma unroll
            for (int i = 0; i < 4; ++i)
                #pragma unroll
                for (int j = 0; j < 4; ++j)
                    acc[i][j] = fmaf(aa[i], bb[j], acc[i][j]);
        }
    }
    #pragma unroll
    for (int i = 0; i < 4; ++i) {
        const int r = row0 + tm*4 + i;
        float4 o4;
        o4.x = acc[i][0] + bout[col0 + tn*4 + 0];
        o4.y = acc[i][1] + bout[col0 + tn*4 + 1];
        o4.z = acc[i][2] + bout[col0 + tn*4 + 2];
        o4.w = acc[i][3] + bout[col0 + tn*4 + 3];
        *(float4*)&out[(size_t)r * EMB + col0 + tn*4] = o4;
    }
}

// ---------------------------------------------------------------------------
extern "C" void kernel_launch(void* const* d_in, const int* in_sizes, int n_in,
                              void* d_out, int out_size, void* d_ws, size_t ws_size,
                              hipStream_t stream) {
    const float* query = (const float*)d_in[0];
    // d_in[1], d_in[2] unused: reference projects q,k,v all from `query`.
    const float* rpb  = (const float*)d_in[3];
    const float* Win  = (const float*)d_in[4];
    const float* bin  = (const float*)d_in[5];
    const float* Wout = (const float*)d_in[6];
    const float* bout = (const float*)d_in[7];

    float* out = (float*)d_out;
    float* att = out + (size_t)S_LEN * BATCH * EMB;   // (B,H,S,S) fp32

    const size_t per = (size_t)BH * S_LEN * HD;       // 4,194,304 elements
    f16*   Qh  = (f16*)d_ws;
    f16*   Kh  = Qh + per;
    f16*   Vt  = Kh + per;
    float* ctx = (float*)(Vt + per);                  // fp32 (SB, E)

    k_qkv    <<<dim3(SB/64, E3/64),   256, 0, stream>>>(query, Win, bin, Qh, Kh, Vt);
    k_attn   <<<dim3(S_LEN/64, BH),   256, 0, stream>>>(Qh, Kh, Vt, rpb, att, ctx);
    k_outproj<<<dim3(SB/64, EMB/64),  256, 0, stream>>>(ctx, Wout, bout, out);
}

// Round 5
// 701.783 us; speedup vs baseline: 1.4485x; 1.0006x over previous
//
#include <hip/hip_runtime.h>
#include <hip/hip_bf16.h>

#define S_LEN 2048
#define BATCH 4
#define EMB   512
#define NH    8
#define HD    64
#define SB    (S_LEN*BATCH)   // 8192
#define E3    (3*EMB)         // 1536
#define BH    (BATCH*NH)      // 32

typedef _Float16 f16;
typedef _Float16 f16x4 __attribute__((ext_vector_type(4)));
typedef _Float16 f16x8 __attribute__((ext_vector_type(8)));
typedef float    f32x4 __attribute__((ext_vector_type(4)));

// ---------------------------------------------------------------------------
// Kernel 1: qkv = query @ W_in^T + b_in  (fp32 SIMD GEMM, proven)
// writes fp16: Qh,Kh as (bh, s, d); V transposed -> Vt (bh, d, s)
// ---------------------------------------------------------------------------
__global__ __launch_bounds__(256) void k_qkv(const float* __restrict__ Q,
    const float* __restrict__ W, const float* __restrict__ bin,
    f16* __restrict__ Qh, f16* __restrict__ Kh, f16* __restrict__ Vt)
{
    __shared__ float As[16][68];
    __shared__ float Bs[16][68];
    const int row0 = blockIdx.x * 64;
    const int col0 = blockIdx.y * 64;
    const int tid = threadIdx.x;
    const int tm = tid & 15, tn = tid >> 4;
    const int lr = tid >> 2;          // 0..63
    const int lk = (tid & 3) * 4;     // 0,4,8,12

    float acc[4][4] = {};
    for (int k0 = 0; k0 < EMB; k0 += 16) {
        float4 a = *(const float4*)&Q[(size_t)(row0 + lr) * EMB + k0 + lk];
        float4 b = *(const float4*)&W[(size_t)(col0 + lr) * EMB + k0 + lk];
        __syncthreads();
        As[lk+0][lr] = a.x; As[lk+1][lr] = a.y; As[lk+2][lr] = a.z; As[lk+3][lr] = a.w;
        Bs[lk+0][lr] = b.x; Bs[lk+1][lr] = b.y; Bs[lk+2][lr] = b.z; Bs[lk+3][lr] = b.w;
        __syncthreads();
        #pragma unroll
        for (int kk = 0; kk < 16; ++kk) {
            float4 av = *(const float4*)&As[kk][tm*4];
            float4 bv = *(const float4*)&Bs[kk][tn*4];
            float aa[4] = {av.x, av.y, av.z, av.w};
            float bb[4] = {bv.x, bv.y, bv.z, bv.w};
            #pragma unroll
            for (int i = 0; i < 4; ++i)
                #pragma unroll
                for (int j = 0; j < 4; ++j)
                    acc[i][j] = fmaf(aa[i], bb[j], acc[i][j]);
        }
    }
    const int which = col0 >> 9;               // 0:q 1:k 2:v
    const int h     = (col0 & 511) >> 6;
    const int dn    = tn * 4;                  // head-dim base (0..60)
    const int s     = (row0 >> 2) + tm;        // seq index
    #pragma unroll
    for (int i = 0; i < 4; ++i) {
        const int b  = i;                      // batch index
        const int bh = b * NH + h;
        float v0 = acc[i][0] + bin[col0 + dn + 0];
        float v1 = acc[i][1] + bin[col0 + dn + 1];
        float v2 = acc[i][2] + bin[col0 + dn + 2];
        float v3 = acc[i][3] + bin[col0 + dn + 3];
        if (which == 2) {
            f16* vt = Vt + ((size_t)bh * HD + dn) * S_LEN + s;
            vt[0 * S_LEN] = (f16)v0;
            vt[1 * S_LEN] = (f16)v1;
            vt[2 * S_LEN] = (f16)v2;
            vt[3 * S_LEN] = (f16)v3;
        } else {
            f16* dst = (which == 0 ? Qh : Kh) + ((size_t)bh * S_LEN + s) * HD + dn;
            f16x4 o;
            o[0] = (f16)v0; o[1] = (f16)v1; o[2] = (f16)v2; o[3] = (f16)v3;
            *(f16x4*)dst = o;
        }
    }
}

// ---------------------------------------------------------------------------
// Kernel 2: fused scores+softmax+PV. 512 threads = 8 waves: wave w handles
// q-rows (w&3)*16.. and k-HALF (w>>2) of [0,2048). Row sums and partial O
// combined across the two k-halves via LDS. Grid: b innermost for bias reuse.
// Fixed softmax shift of 30 (scores clipped to ±30) == reference softmax.
// ---------------------------------------------------------------------------
__global__ __launch_bounds__(512) void k_attn(
    const f16* __restrict__ Qh, const f16* __restrict__ Kh, const f16* __restrict__ Vt,
    const float* __restrict__ rpb, float* __restrict__ att, float* __restrict__ ctx)
{
    __shared__ f16   Pw[8][1024];     // per-wave 16(q) x 64(k), 16B-chunk XOR swizzle
    __shared__ float obuf[4][16][64]; // partial O from k-half 1: [wq][qrow][d]
    __shared__ float lsum[8][16];     // per-wave row sums
    const int tid = threadIdx.x;
    const int w  = tid >> 6;        // 0..7
    const int l  = tid & 63;
    const int g  = l >> 4;          // lane group 0..3
    const int li = l & 15;          // lane-in-group = this lane's q-row
    const int wq = w & 3;           // row group
    const int kh = w >> 2;          // k-half (0 or 1)
    const int bx = blockIdx.x;
    const int b  = bx & 3;          // innermost: bias-sharing blocks adjacent
    const int rt = (bx >> 2) & 31;
    const int h  = bx >> 7;
    const int bh = b * NH + h;
    const int r0 = rt * 64 + wq * 16;          // wave's q-row base
    const int row_l = r0 + li;                 // this lane's q-row
    const int t0 = kh * 16;                    // this wave's k-tile range [t0,t0+16)

    // Q fragment (B-operand): B[k=g*8+j][col=li] = Q[row_l][k]
    const f16* qbase = Qh + ((size_t)bh * S_LEN + row_l) * HD;
    const f16x8 bq0 = *(const f16x8*)(qbase + g * 8);
    const f16x8 bq1 = *(const f16x8*)(qbase + 32 + g * 8);

    const f16*   kbase = Kh  + (size_t)bh * S_LEN * HD;
    const f16*   vtb   = Vt  + (size_t)bh * HD * S_LEN;
    const float* brow  = rpb + ((size_t)h * S_LEN + row_l) * S_LEN;   // lane's bias row
    float*       arow  = att + ((size_t)bh * S_LEN + row_l) * S_LEN;  // lane's att row

    const f32x4 zero = {0.f, 0.f, 0.f, 0.f};
    float ls = 0.f;

    // ---------------- PASS 1: per-row partial sums of exp(S-30) ----------------
    for (int t = t0; t < t0 + 16; ++t) {
        const int c0 = t * 64;
        #pragma unroll
        for (int n = 0; n < 4; ++n) {
            const f16* kp = kbase + (size_t)(c0 + n*16 + li) * HD + g * 8;
            f16x8 ak0 = *(const f16x8*)kp;
            f16x8 ak1 = *(const f16x8*)(kp + 32);
            f32x4 bv = *(const f32x4*)&brow[c0 + n*16 + g*4];
            f32x4 st = __builtin_amdgcn_mfma_f32_16x16x32_f16(ak0, bq0, zero, 0, 0, 0);
            st = __builtin_amdgcn_mfma_f32_16x16x32_f16(ak1, bq1, st, 0, 0, 0);
            #pragma unroll
            for (int jj = 0; jj < 4; ++jj) {
                float bc = fminf(fmaxf(bv[jj], -5.f), 5.f) * 0.05f;
                float v  = st[jj] * 0.125f + bc;
                v = fminf(fmaxf(v, -30.f), 30.f);
                ls += __expf(v - 30.f);
            }
        }
    }
    // reduce across the 4 lanes (g) sharing this q-row, then across k-halves
    ls += __shfl_xor(ls, 16);
    ls += __shfl_xor(ls, 32);
    if (l < 16) lsum[w][l] = ls;
    __syncthreads();
    const float inv = 1.0f / (lsum[wq][li] + lsum[4 + wq][li]);

    // ---------------- PASS 2: normalized weights + partial PV ----------------
    f32x4 o[4];
    #pragma unroll
    for (int n = 0; n < 4; ++n) o[n] = zero;
    f16* pw = &Pw[w][0];

    for (int t = t0; t < t0 + 16; ++t) {
        const int c0 = t * 64;
        #pragma unroll
        for (int n = 0; n < 4; ++n) {
            const f16* kp = kbase + (size_t)(c0 + n*16 + li) * HD + g * 8;
            f16x8 ak0 = *(const f16x8*)kp;
            f16x8 ak1 = *(const f16x8*)(kp + 32);
            f32x4 bv = *(const f32x4*)&brow[c0 + n*16 + g*4];
            f32x4 st = __builtin_amdgcn_mfma_f32_16x16x32_f16(ak0, bq0, zero, 0, 0, 0);
            st = __builtin_amdgcn_mfma_f32_16x16x32_f16(ak1, bq1, st, 0, 0, 0);
            f32x4 w4;
            f16x4 p4;
            #pragma unroll
            for (int jj = 0; jj < 4; ++jj) {
                float bc = fminf(fmaxf(bv[jj], -5.f), 5.f) * 0.05f;
                float v  = st[jj] * 0.125f + bc;
                v = fminf(fmaxf(v, -30.f), 30.f);
                float wt = __expf(v - 30.f) * inv;
                w4[jj] = wt;
                p4[jj] = (f16)wt;
            }
            // normalized weights -> att (nontemporal: keep LLC for bias)
            __builtin_nontemporal_store(w4, (f32x4*)&arow[c0 + n*16 + g*4]);
            // P^T -> LDS [q=li][k=n*16+g*4..+3], 16B-chunk XOR swizzle
            const int pc = ((n*2 + (g >> 1)) ^ li) & 7;   // phys 16B chunk (0..7)
            *(f16x4*)(pw + li*64 + pc*8 + (g & 1)*4) = p4;
        }
        // PV: O = mfma(A=P, B=V^T-frag). A-frag: row=li, k=g*8+j (b128 reads)
        f16x8 pa0 = *(const f16x8*)(pw + li*64 + ((g ^ li) & 7) * 8);
        f16x8 pa1 = *(const f16x8*)(pw + li*64 + (((4 + g) ^ li) & 7) * 8);
        #pragma unroll
        for (int n = 0; n < 4; ++n) {
            const f16* vp = vtb + (size_t)(n*16 + li) * S_LEN + c0 + g * 8;
            f16x8 v0 = *(const f16x8*)vp;
            f16x8 v1 = *(const f16x8*)(vp + 32);
            o[n] = __builtin_amdgcn_mfma_f32_16x16x32_f16(pa0, v0, o[n], 0, 0, 0);
            o[n] = __builtin_amdgcn_mfma_f32_16x16x32_f16(pa1, v1, o[n], 0, 0, 0);
        }
    }

    // ---------------- combine k-half partial O, epilogue ----------------
    if (kh == 1) {
        #pragma unroll
        for (int n = 0; n < 4; ++n)
            #pragma unroll
            for (int jj = 0; jj < 4; ++jj)
                obuf[wq][g*4 + jj][n*16 + li] = o[n][jj];
    }
    __syncthreads();
    if (kh == 0) {
        #pragma unroll
        for (int n = 0; n < 4; ++n) {
            #pragma unroll
            for (int jj = 0; jj < 4; ++jj) {
                const int row = r0 + g*4 + jj;
                float v = o[n][jj] + obuf[wq][g*4 + jj][n*16 + li];
                v = fminf(fmaxf(v, -10.f), 10.f);
                ctx[((size_t)row * BATCH + b) * EMB + h * HD + n*16 + li] = v;
            }
        }
    }
}

// ---------------------------------------------------------------------------
// Kernel 3: out = ctx @ W_out^T + b_out  (fp32 SIMD GEMM, proven)
// ---------------------------------------------------------------------------
__global__ __launch_bounds__(256) void k_outproj(const float* __restrict__ C,
    const float* __restrict__ W, const float* __restrict__ bout,
    float* __restrict__ out)
{
    __shared__ float As[16][68];
    __shared__ float Bs[16][68];
    const int row0 = blockIdx.x * 64;
    const int col0 = blockIdx.y * 64;
    const int tid = threadIdx.x;
    const int tm = tid & 15, tn = tid >> 4;
    const int lr = tid >> 2;
    const int lk = (tid & 3) * 4;

    float acc[4][4] = {};
    for (int k0 = 0; k0 < EMB; k0 += 16) {
        float4 a = *(const float4*)&C[(size_t)(row0 + lr) * EMB + k0 + lk];
        float4 b = *(const float4*)&W[(size_t)(col0 + lr) * EMB + k0 + lk];
        __syncthreads();
        As[lk+0][lr] = a.x; As[lk+1][lr] = a.y; As[lk+2][lr] = a.z; As[lk+3][lr] = a.w;
        Bs[lk+0][lr] = b.x; Bs[lk+1][lr] = b.y; Bs[lk+2][lr] = b.z; Bs[lk+3][lr] = b.w;
        __syncthreads();
        #pragma unroll
        for (int kk = 0; kk < 16; ++kk) {
            float4 av = *(const float4*)&As[kk][tm*4];
            float4 bv = *(const float4*)&Bs[kk][tn*4];
            float aa[4] = {av.x, av.y, av.z, av.w};
            float bb[4] = {bv.x, bv.y, bv.z, bv.w};
            #pragma unroll
            for (int i = 0; i < 4; ++i)
                #pragma unroll
                for (int j = 0; j < 4; ++j)
                    acc[i][j] = fmaf(aa[i], bb[j], acc[i][j]);
        }
    }
    #pragma unroll
    for (int i = 0; i < 4; ++i) {
        const int r = row0 + tm*4 + i;
        float4 o4;
        o4.x = acc[i][0] + bout[col0 + tn*4 + 0];
        o4.y = acc[i][1] + bout[col0 + tn*4 + 1];
        o4.z = acc[i][2] + bout[col0 + tn*4 + 2];
        o4.w = acc[i][3] + bout[col0 + tn*4 + 3];
        *(float4*)&out[(size_t)r * EMB + col0 + tn*4] = o4;
    }
}

// ---------------------------------------------------------------------------
extern "C" void kernel_launch(void* const* d_in, const int* in_sizes, int n_in,
                              void* d_out, int out_size, void* d_ws, size_t ws_size,
                              hipStream_t stream) {
    const float* query = (const float*)d_in[0];
    // d_in[1], d_in[2] unused: reference projects q,k,v all from `query`.
    const float* rpb  = (const float*)d_in[3];
    const float* Win  = (const float*)d_in[4];
    const float* bin  = (const float*)d_in[5];
    const float* Wout = (const float*)d_in[6];
    const float* bout = (const float*)d_in[7];

    float* out = (float*)d_out;
    float* att = out + (size_t)S_LEN * BATCH * EMB;   // (B,H,S,S) fp32

    const size_t per = (size_t)BH * S_LEN * HD;       // 4,194,304 elements
    f16*   Qh  = (f16*)d_ws;
    f16*   Kh  = Qh + per;
    f16*   Vt  = Kh + per;
    float* ctx = (float*)(Vt + per);                  // fp32 (SB, E)

    k_qkv    <<<dim3(SB/64, E3/64),   256, 0, stream>>>(query, Win, bin, Qh, Kh, Vt);
    k_attn   <<<dim3(4 * 32 * NH),    512, 0, stream>>>(Qh, Kh, Vt, rpb, att, ctx);
    k_outproj<<<dim3(SB/64, EMB/64),  256, 0, stream>>>(ctx, Wout, bout, out);
}

// Round 6
// 472.316 us; speedup vs baseline: 2.1522x; 1.4858x over previous
//
#include <hip/hip_runtime.h>
#include <hip/hip_bf16.h>

#define S_LEN 2048
#define BATCH 4
#define EMB   512
#define NH    8
#define HD    64
#define SB    (S_LEN*BATCH)   // 8192
#define E3    (3*EMB)         // 1536
#define BH    (BATCH*NH)      // 32

typedef _Float16 f16;
typedef _Float16 f16x4 __attribute__((ext_vector_type(4)));
typedef _Float16 f16x8 __attribute__((ext_vector_type(8)));
typedef float    f32x4 __attribute__((ext_vector_type(4)));

// intra-wave LDS write->read ordering fence (cross-lane): wait DS ops, pin scheduler
#define LDS_FENCE() do { asm volatile("s_waitcnt lgkmcnt(0)" ::: "memory"); \
                         __builtin_amdgcn_sched_barrier(0); } while (0)

// ---------------------------------------------------------------------------
// Kernel 1: qkv = query @ W_in^T + b_in  (fp32 SIMD GEMM, proven)
// writes fp16: Qh,Kh as (bh, s, d); V transposed -> Vt (bh, d, s)
// ---------------------------------------------------------------------------
__global__ __launch_bounds__(256) void k_qkv(const float* __restrict__ Q,
    const float* __restrict__ W, const float* __restrict__ bin,
    f16* __restrict__ Qh, f16* __restrict__ Kh, f16* __restrict__ Vt)
{
    __shared__ float As[16][68];
    __shared__ float Bs[16][68];
    const int row0 = blockIdx.x * 64;
    const int col0 = blockIdx.y * 64;
    const int tid = threadIdx.x;
    const int tm = tid & 15, tn = tid >> 4;
    const int lr = tid >> 2;          // 0..63
    const int lk = (tid & 3) * 4;     // 0,4,8,12

    float acc[4][4] = {};
    for (int k0 = 0; k0 < EMB; k0 += 16) {
        float4 a = *(const float4*)&Q[(size_t)(row0 + lr) * EMB + k0 + lk];
        float4 b = *(const float4*)&W[(size_t)(col0 + lr) * EMB + k0 + lk];
        __syncthreads();
        As[lk+0][lr] = a.x; As[lk+1][lr] = a.y; As[lk+2][lr] = a.z; As[lk+3][lr] = a.w;
        Bs[lk+0][lr] = b.x; Bs[lk+1][lr] = b.y; Bs[lk+2][lr] = b.z; Bs[lk+3][lr] = b.w;
        __syncthreads();
        #pragma unroll
        for (int kk = 0; kk < 16; ++kk) {
            float4 av = *(const float4*)&As[kk][tm*4];
            float4 bv = *(const float4*)&Bs[kk][tn*4];
            float aa[4] = {av.x, av.y, av.z, av.w};
            float bb[4] = {bv.x, bv.y, bv.z, bv.w};
            #pragma unroll
            for (int i = 0; i < 4; ++i)
                #pragma unroll
                for (int j = 0; j < 4; ++j)
                    acc[i][j] = fmaf(aa[i], bb[j], acc[i][j]);
        }
    }
    const int which = col0 >> 9;               // 0:q 1:k 2:v
    const int h     = (col0 & 511) >> 6;
    const int dn    = tn * 4;                  // head-dim base (0..60)
    const int s     = (row0 >> 2) + tm;        // seq index
    #pragma unroll
    for (int i = 0; i < 4; ++i) {
        const int b  = i;                      // batch index
        const int bh = b * NH + h;
        float v0 = acc[i][0] + bin[col0 + dn + 0];
        float v1 = acc[i][1] + bin[col0 + dn + 1];
        float v2 = acc[i][2] + bin[col0 + dn + 2];
        float v3 = acc[i][3] + bin[col0 + dn + 3];
        if (which == 2) {
            f16* vt = Vt + ((size_t)bh * HD + dn) * S_LEN + s;
            vt[0 * S_LEN] = (f16)v0;
            vt[1 * S_LEN] = (f16)v1;
            vt[2 * S_LEN] = (f16)v2;
            vt[3 * S_LEN] = (f16)v3;
        } else {
            f16* dst = (which == 0 ? Qh : Kh) + ((size_t)bh * S_LEN + s) * HD + dn;
            f16x4 o;
            o[0] = (f16)v0; o[1] = (f16)v1; o[2] = (f16)v2; o[3] = (f16)v3;
            *(f16x4*)dst = o;
        }
    }
}

// ---------------------------------------------------------------------------
// Kernel 2: fused scores+softmax+PV. 256 thr = 4 waves, each 16 q-rows; all
// waves share LDS-staged K/V tiles (reg-staged one tile ahead). Scores go
// MFMA-layout -> per-wave swizzled LDS -> row-layout (8 lanes/q-row) so bias
// loads and att stores are 128B-contiguous per row. P back to LDS in the
// verified swizzled layout -> PV MFMA with V-frags from LDS.
// Fixed softmax shift of 30 (scores clipped ±30) == reference softmax.
// ---------------------------------------------------------------------------
__global__ __launch_bounds__(256, 4) void k_attn(
    const f16* __restrict__ Qh, const f16* __restrict__ Kh, const f16* __restrict__ Vt,
    const float* __restrict__ rpb, float* __restrict__ att, float* __restrict__ ctx)
{
    __shared__ f16   KT[64*64];        // [krow][d-chunk], phys16B = c ^ (krow&7)
    __shared__ f16   VTs[64*64];       // [drow][s-chunk], phys16B = c ^ (drow&7)
    __shared__ float SBm[4][16*64];    // per-wave scores [q][k], phys16B = c ^ (q&7)
    __shared__ f16   PBm[4][16*64];    // per-wave P      [q][k], phys16B = c ^ (q&7)

    const int tid = threadIdx.x;
    const int w  = tid >> 6, l = tid & 63;
    const int g  = l >> 4, li = l & 15;
    const int l8 = l >> 3, l7 = l & 7;
    const int bx = blockIdx.x;
    const int b  = bx & 3;                 // innermost: bias-sharing blocks adjacent
    const int rt = (bx >> 2) & 31;
    const int h  = bx >> 7;
    const int bh = b * NH + h;
    const int r0 = rt * 64 + w * 16;       // wave's q-row base

    // Q fragments (B-operand), loaded once
    const f16* qbase = Qh + ((size_t)bh * S_LEN + r0 + li) * HD;
    const f16x8 bq0 = *(const f16x8*)(qbase + g * 8);
    const f16x8 bq1 = *(const f16x8*)(qbase + 32 + g * 8);

    // staging lane constants: wave w stages rows w*16..+16 of each 64-row tile
    const int sr0 = w * 16 + l8;           // j=0 row (also = d-row for V)
    const int sr1 = sr0 + 8;               // j=1 row
    const int scl = (l7 ^ l8) * 8;         // logical f16 col (16B-chunk swizzle, key row&7=l8)
    const f16* kg0 = Kh + ((size_t)bh * S_LEN + sr0) * HD + scl;
    const f16* kg1 = Kh + ((size_t)bh * S_LEN + sr1) * HD + scl;
    const f16* vg0 = Vt + ((size_t)bh * HD + sr0) * S_LEN + scl;
    const f16* vg1 = Vt + ((size_t)bh * HD + sr1) * S_LEN + scl;
    const int stw0 = (w * 2 + 0) * 512 + l * 8;   // f16 idx of this lane's 16B slot
    const int stw1 = (w * 2 + 1) * 512 + l * 8;

    // fragment read offsets (KT / VTs / PB share geometry; add n*1024 for tile n)
    const int fK0 = li * 64 + ((g ^ (li & 7)) << 3);
    const int fK1 = li * 64 + (((g + 4) ^ (li & 7)) << 3);

    float* SBw = &SBm[w][0];
    f16*   PBw = &PBm[w][0];
    const int sbr = l8 * 64 + ((l7 ^ l8) << 2);   // + i*512 + half*32

    // row-layout global pointers (q-row = r0 + i*8 + l8, col base l7*4)
    const float* bias0 = rpb + ((size_t)h * S_LEN + r0 + l8) * S_LEN + l7 * 4;
    const float* bias1 = bias0 + (size_t)8 * S_LEN;
    float* att0 = att + ((size_t)bh * S_LEN + r0 + l8) * S_LEN + l7 * 4;
    float* att1 = att0 + (size_t)8 * S_LEN;

    const f32x4 zero = {0.f, 0.f, 0.f, 0.f};

    // =================== PASS 1: row sums of exp(S-30) ===================
    float ls0 = 0.f, ls1 = 0.f;
    f16x8 tk0 = *(const f16x8*)kg0;
    f16x8 tk1 = *(const f16x8*)kg1;
    for (int t = 0; t < 32; ++t) {
        __syncthreads();                        // prior tile reads done
        *(f16x8*)&KT[stw0] = tk0;
        *(f16x8*)&KT[stw1] = tk1;
        __syncthreads();                        // tile t visible
        const int tn1 = (t < 31) ? t + 1 : 31;  // prefetch next (in flight over compute)
        tk0 = *(const f16x8*)(kg0 + (size_t)tn1 * 4096);
        tk1 = *(const f16x8*)(kg1 + (size_t)tn1 * 4096);
        #pragma unroll
        for (int half = 0; half < 2; ++half) {
            #pragma unroll
            for (int n2 = 0; n2 < 2; ++n2) {
                const int n = half * 2 + n2;
                f16x8 a0 = *(const f16x8*)&KT[n * 1024 + fK0];
                f16x8 a1 = *(const f16x8*)&KT[n * 1024 + fK1];
                f32x4 st = __builtin_amdgcn_mfma_f32_16x16x32_f16(a0, bq0, zero, 0, 0, 0);
                st = __builtin_amdgcn_mfma_f32_16x16x32_f16(a1, bq1, st, 0, 0, 0);
                *(f32x4*)&SBw[li * 64 + ((((n * 4) + g) ^ (li & 7)) << 2)] = st;
            }
            LDS_FENCE();
            #pragma unroll
            for (int i = 0; i < 2; ++i) {
                f32x4 sc = *(const f32x4*)&SBw[sbr + i * 512 + half * 32];
                f32x4 bz = *(const f32x4*)((i ? bias1 : bias0) + t * 64 + half * 32);
                float acc = 0.f;
                #pragma unroll
                for (int jj = 0; jj < 4; ++jj) {
                    float bc = fminf(fmaxf(bz[jj], -5.f), 5.f) * 0.05f;
                    float v  = sc[jj] * 0.125f + bc;
                    v = fminf(fmaxf(v, -30.f), 30.f);
                    acc += __expf(v - 30.f);
                }
                if (i) ls1 += acc; else ls0 += acc;
            }
        }
    }
    ls0 += __shfl_xor(ls0, 1); ls0 += __shfl_xor(ls0, 2); ls0 += __shfl_xor(ls0, 4);
    ls1 += __shfl_xor(ls1, 1); ls1 += __shfl_xor(ls1, 2); ls1 += __shfl_xor(ls1, 4);
    const float inv0 = 1.0f / ls0;
    const float inv1 = 1.0f / ls1;

    // =================== PASS 2: weights + PV ===================
    f32x4 o[4] = {zero, zero, zero, zero};
    tk0 = *(const f16x8*)kg0;
    tk1 = *(const f16x8*)kg1;
    f16x8 tv0 = *(const f16x8*)vg0;
    f16x8 tv1 = *(const f16x8*)vg1;
    for (int t = 0; t < 32; ++t) {
        __syncthreads();
        *(f16x8*)&KT[stw0]  = tk0;
        *(f16x8*)&KT[stw1]  = tk1;
        *(f16x8*)&VTs[stw0] = tv0;
        *(f16x8*)&VTs[stw1] = tv1;
        __syncthreads();
        const int tn1 = (t < 31) ? t + 1 : 31;
        tk0 = *(const f16x8*)(kg0 + (size_t)tn1 * 4096);
        tk1 = *(const f16x8*)(kg1 + (size_t)tn1 * 4096);
        tv0 = *(const f16x8*)(vg0 + (size_t)tn1 * 64);
        tv1 = *(const f16x8*)(vg1 + (size_t)tn1 * 64);
        #pragma unroll
        for (int half = 0; half < 2; ++half) {
            #pragma unroll
            for (int n2 = 0; n2 < 2; ++n2) {
                const int n = half * 2 + n2;
                f16x8 a0 = *(const f16x8*)&KT[n * 1024 + fK0];
                f16x8 a1 = *(const f16x8*)&KT[n * 1024 + fK1];
                f32x4 st = __builtin_amdgcn_mfma_f32_16x16x32_f16(a0, bq0, zero, 0, 0, 0);
                st = __builtin_amdgcn_mfma_f32_16x16x32_f16(a1, bq1, st, 0, 0, 0);
                *(f32x4*)&SBw[li * 64 + ((((n * 4) + g) ^ (li & 7)) << 2)] = st;
            }
            LDS_FENCE();
            #pragma unroll
            for (int i = 0; i < 2; ++i) {
                f32x4 sc = *(const f32x4*)&SBw[sbr + i * 512 + half * 32];
                f32x4 bz = *(const f32x4*)((i ? bias1 : bias0) + t * 64 + half * 32);
                const float invi = i ? inv1 : inv0;
                f32x4 w4;
                f16x4 p4;
                #pragma unroll
                for (int jj = 0; jj < 4; ++jj) {
                    float bc = fminf(fmaxf(bz[jj], -5.f), 5.f) * 0.05f;
                    float v  = sc[jj] * 0.125f + bc;
                    v = fminf(fmaxf(v, -30.f), 30.f);
                    float wt = __expf(v - 30.f) * invi;
                    w4[jj] = wt;
                    p4[jj] = (f16)wt;
                }
                __builtin_nontemporal_store(w4,
                    (f32x4*)((i ? att1 : att0) + t * 64 + half * 32));
                // P -> LDS [q = i*8+l8][k 16B-chunk c = half*4 + (l7>>1)], phys = c ^ (q&7)=c^l8
                *(f16x4*)&PBw[(i * 8 + l8) * 64 +
                              (((half * 4 + (l7 >> 1)) ^ l8) << 3) + ((l & 1) << 2)] = p4;
            }
        }
        LDS_FENCE();
        const f16x8 pa0 = *(const f16x8*)&PBw[fK0];
        const f16x8 pa1 = *(const f16x8*)&PBw[fK1];
        #pragma unroll
        for (int n = 0; n < 4; ++n) {
            f16x8 v0 = *(const f16x8*)&VTs[n * 1024 + fK0];
            f16x8 v1 = *(const f16x8*)&VTs[n * 1024 + fK1];
            o[n] = __builtin_amdgcn_mfma_f32_16x16x32_f16(pa0, v0, o[n], 0, 0, 0);
            o[n] = __builtin_amdgcn_mfma_f32_16x16x32_f16(pa1, v1, o[n], 0, 0, 0);
        }
    }

    // epilogue: ctx[(s*B + b)*E + h*64 + d], clipped ±10
    #pragma unroll
    for (int n = 0; n < 4; ++n) {
        #pragma unroll
        for (int jj = 0; jj < 4; ++jj) {
            const int row = r0 + g * 4 + jj;
            float v = fminf(fmaxf(o[n][jj], -10.f), 10.f);
            ctx[((size_t)row * BATCH + b) * EMB + h * HD + n * 16 + li] = v;
        }
    }
}

// ---------------------------------------------------------------------------
// Kernel 3: out = ctx @ W_out^T + b_out  (fp32 SIMD GEMM, proven)
// ---------------------------------------------------------------------------
__global__ __launch_bounds__(256) void k_outproj(const float* __restrict__ C,
    const float* __restrict__ W, const float* __restrict__ bout,
    float* __restrict__ out)
{
    __shared__ float As[16][68];
    __shared__ float Bs[16][68];
    const int row0 = blockIdx.x * 64;
    const int col0 = blockIdx.y * 64;
    const int tid = threadIdx.x;
    const int tm = tid & 15, tn = tid >> 4;
    const int lr = tid >> 2;
    const int lk = (tid & 3) * 4;

    float acc[4][4] = {};
    for (int k0 = 0; k0 < EMB; k0 += 16) {
        float4 a = *(const float4*)&C[(size_t)(row0 + lr) * EMB + k0 + lk];
        float4 b = *(const float4*)&W[(size_t)(col0 + lr) * EMB + k0 + lk];
        __syncthreads();
        As[lk+0][lr] = a.x; As[lk+1][lr] = a.y; As[lk+2][lr] = a.z; As[lk+3][lr] = a.w;
        Bs[lk+0][lr] = b.x; Bs[lk+1][lr] = b.y; Bs[lk+2][lr] = b.z; Bs[lk+3][lr] = b.w;
        __syncthreads();
        #pragma unroll
        for (int kk = 0; kk < 16; ++kk) {
            float4 av = *(const float4*)&As[kk][tm*4];
            float4 bv = *(const float4*)&Bs[kk][tn*4];
            float aa[4] = {av.x, av.y, av.z, av.w};
            float bb[4] = {bv.x, bv.y, bv.z, bv.w};
            #pragma unroll
            for (int i = 0; i < 4; ++i)
                #pragma unroll
                for (int j = 0; j < 4; ++j)
                    acc[i][j] = fmaf(aa[i], bb[j], acc[i][j]);
        }
    }
    #pragma unroll
    for (int i = 0; i < 4; ++i) {
        const int r = row0 + tm*4 + i;
        float4 o4;
        o4.x = acc[i][0] + bout[col0 + tn*4 + 0];
        o4.y = acc[i][1] + bout[col0 + tn*4 + 1];
        o4.z = acc[i][2] + bout[col0 + tn*4 + 2];
        o4.w = acc[i][3] + bout[col0 + tn*4 + 3];
        *(float4*)&out[(size_t)r * EMB + col0 + tn*4] = o4;
    }
}

// ---------------------------------------------------------------------------
extern "C" void kernel_launch(void* const* d_in, const int* in_sizes, int n_in,
                              void* d_out, int out_size, void* d_ws, size_t ws_size,
                              hipStream_t stream) {
    const float* query = (const float*)d_in[0];
    // d_in[1], d_in[2] unused: reference projects q,k,v all from `query`.
    const float* rpb  = (const float*)d_in[3];
    const float* Win  = (const float*)d_in[4];
    const float* bin  = (const float*)d_in[5];
    const float* Wout = (const float*)d_in[6];
    const float* bout = (const float*)d_in[7];

    float* out = (float*)d_out;
    float* att = out + (size_t)S_LEN * BATCH * EMB;   // (B,H,S,S) fp32

    const size_t per = (size_t)BH * S_LEN * HD;       // 4,194,304 elements
    f16*   Qh  = (f16*)d_ws;
    f16*   Kh  = Qh + per;
    f16*   Vt  = Kh + per;
    float* ctx = (float*)(Vt + per);                  // fp32 (SB, E)

    k_qkv    <<<dim3(SB/64, E3/64),   256, 0, stream>>>(query, Win, bin, Qh, Kh, Vt);
    k_attn   <<<dim3(4 * 32 * NH),    256, 0, stream>>>(Qh, Kh, Vt, rpb, att, ctx);
    k_outproj<<<dim3(SB/64, EMB/64),  256, 0, stream>>>(ctx, Wout, bout, out);
}

// Round 7
// 287.997 us; speedup vs baseline: 3.5296x; 1.6400x over previous
//
#include <hip/hip_runtime.h>
#include <hip/hip_bf16.h>

#define S_LEN 2048
#define BATCH 4
#define EMB   512
#define NH    8
#define HD    64
#define SB    (S_LEN*BATCH)   // 8192
#define E3    (3*EMB)         // 1536
#define BH    (BATCH*NH)      // 32

typedef _Float16 f16;
typedef _Float16 f16x4 __attribute__((ext_vector_type(4)));
typedef _Float16 f16x8 __attribute__((ext_vector_type(8)));
typedef float    f32x4 __attribute__((ext_vector_type(4)));

// intra-wave LDS write->read ordering fence (cross-lane): wait DS ops, pin scheduler
#define LDS_FENCE() do { asm volatile("s_waitcnt lgkmcnt(0)" ::: "memory"); \
                         __builtin_amdgcn_sched_barrier(0); } while (0)

// ---------------------------------------------------------------------------
// Kernel 0: cast query / W_in / W_out to fp16 (contiguous, vectorized)
// ---------------------------------------------------------------------------
__global__ __launch_bounds__(256) void k_cast(const float* __restrict__ q,
    const float* __restrict__ wi, const float* __restrict__ wo,
    f16* __restrict__ qh, f16* __restrict__ wih, f16* __restrict__ woh)
{
    const int NQ4 = (SB*EMB)/4, NW4 = (E3*EMB)/4, NO4 = (EMB*EMB)/4;
    const int total = NQ4 + NW4 + NO4;
    for (int i = blockIdx.x * 256 + threadIdx.x; i < total; i += gridDim.x * 256) {
        const float* src; f16* dst; int j;
        if (i < NQ4)            { src = q;  dst = qh;  j = i; }
        else if (i < NQ4 + NW4) { src = wi; dst = wih; j = i - NQ4; }
        else                    { src = wo; dst = woh; j = i - NQ4 - NW4; }
        f32x4 v = *(const f32x4*)(src + (size_t)j * 4);
        f16x4 h4;
        #pragma unroll
        for (int jj = 0; jj < 4; ++jj) h4[jj] = (f16)v[jj];
        *(f16x4*)(dst + (size_t)j * 4) = h4;
    }
}

// ---------------------------------------------------------------------------
// Kernel 1: qkv = query @ W_in^T + b_in  — fp16 MFMA GEMM, 128x128 tile, BK=64.
// A = queryh [8192][512], B = Winh [1536][512] (row-major [n][k] = B^T form).
// Epilogue scatters fp16: Qh,Kh (bh,s,d); Vt (bh,d,s).
// ---------------------------------------------------------------------------
__global__ __launch_bounds__(256) void k_qkv_h(const f16* __restrict__ Ah,
    const f16* __restrict__ Bw, const float* __restrict__ bin,
    f16* __restrict__ Qh, f16* __restrict__ Kh, f16* __restrict__ Vt)
{
    __shared__ f16 As[128 * 64];   // [row][chunk], phys16B = c ^ (row&7)
    __shared__ f16 Bs[128 * 64];
    const int tid = threadIdx.x;
    const int w = tid >> 6, l = tid & 63;
    const int g = l >> 4, li = l & 15;
    const int wm = w >> 1, wn = w & 1;
    const int row0 = blockIdx.x * 128;
    const int col0 = blockIdx.y * 128;

    const int srow = tid >> 3;          // 0..31
    const int sch  = tid & 7;           // logical 16B chunk
    const f16* ga = Ah + (size_t)(row0 + srow) * EMB + sch * 8;
    const f16* gb = Bw + (size_t)(col0 + srow) * EMB + sch * 8;

    f16x8 ra[4], rb[4];
    #pragma unroll
    for (int r = 0; r < 4; ++r) {
        ra[r] = *(const f16x8*)(ga + (size_t)r * 32 * EMB);
        rb[r] = *(const f16x8*)(gb + (size_t)r * 32 * EMB);
    }

    f32x4 acc[4][4];
    const f32x4 zero = {0.f, 0.f, 0.f, 0.f};
    #pragma unroll
    for (int m = 0; m < 4; ++m)
        #pragma unroll
        for (int n = 0; n < 4; ++n) acc[m][n] = zero;

    for (int kt = 0; kt < 8; ++kt) {
        __syncthreads();
        #pragma unroll
        for (int r = 0; r < 4; ++r) {
            const int rw = srow + 32 * r;
            const int po = rw * 64 + ((sch ^ (rw & 7)) << 3);
            *(f16x8*)&As[po] = ra[r];
            *(f16x8*)&Bs[po] = rb[r];
        }
        __syncthreads();
        if (kt < 7) {
            const int kn = (kt + 1) * 64;
            #pragma unroll
            for (int r = 0; r < 4; ++r) {
                ra[r] = *(const f16x8*)(ga + kn + (size_t)r * 32 * EMB);
                rb[r] = *(const f16x8*)(gb + kn + (size_t)r * 32 * EMB);
            }
        }
        #pragma unroll
        for (int kb = 0; kb < 2; ++kb) {
            f16x8 af[4], bf[4];
            #pragma unroll
            for (int m = 0; m < 4; ++m)
                af[m] = *(const f16x8*)&As[(wm*64 + m*16 + li) * 64 +
                                           (((kb*4 + g) ^ (li & 7)) << 3)];
            #pragma unroll
            for (int n = 0; n < 4; ++n)
                bf[n] = *(const f16x8*)&Bs[(wn*64 + n*16 + li) * 64 +
                                           (((kb*4 + g) ^ (li & 7)) << 3)];
            #pragma unroll
            for (int m = 0; m < 4; ++m)
                #pragma unroll
                for (int n = 0; n < 4; ++n)
                    acc[m][n] = __builtin_amdgcn_mfma_f32_16x16x32_f16(af[m], bf[n], acc[m][n], 0, 0, 0);
        }
    }

    // epilogue: C[r = row0+wm*64+m*16+g*4+jj][col = col0+wn*64+n*16+li]; b = jj
    #pragma unroll
    for (int n = 0; n < 4; ++n) {
        const int coln  = col0 + wn*64 + n*16 + li;
        const int which = coln >> 9;
        const int h     = (coln >> 6) & 7;
        const int d     = coln & 63;
        const float bb  = bin[coln];
        #pragma unroll
        for (int m = 0; m < 4; ++m) {
            const int rbase = row0 + wm*64 + m*16 + g*4;
            const int s = rbase >> 2;
            #pragma unroll
            for (int jj = 0; jj < 4; ++jj) {
                const float v = acc[m][n][jj] + bb;
                const int bh = jj * NH + h;
                if (which == 2)
                    Vt[((size_t)bh * HD + d) * S_LEN + s] = (f16)v;
                else
                    (which ? Kh : Qh)[((size_t)bh * S_LEN + s) * HD + d] = (f16)v;
            }
        }
    }
}

// ---------------------------------------------------------------------------
// Kernel 2: fused scores+softmax+PV (round-6 verified). ctx now stored fp16.
// ---------------------------------------------------------------------------
__global__ __launch_bounds__(256, 4) void k_attn(
    const f16* __restrict__ Qh, const f16* __restrict__ Kh, const f16* __restrict__ Vt,
    const float* __restrict__ rpb, float* __restrict__ att, f16* __restrict__ ctxh)
{
    __shared__ f16   KT[64*64];        // [krow][d-chunk], phys16B = c ^ (krow&7)
    __shared__ f16   VTs[64*64];       // [drow][s-chunk], phys16B = c ^ (drow&7)
    __shared__ float SBm[4][16*64];    // per-wave scores [q][k], phys16B = c ^ (q&7)
    __shared__ f16   PBm[4][16*64];    // per-wave P      [q][k], phys16B = c ^ (q&7)

    const int tid = threadIdx.x;
    const int w  = tid >> 6, l = tid & 63;
    const int g  = l >> 4, li = l & 15;
    const int l8 = l >> 3, l7 = l & 7;
    const int bx = blockIdx.x;
    const int b  = bx & 3;
    const int rt = (bx >> 2) & 31;
    const int h  = bx >> 7;
    const int bh = b * NH + h;
    const int r0 = rt * 64 + w * 16;

    const f16* qbase = Qh + ((size_t)bh * S_LEN + r0 + li) * HD;
    const f16x8 bq0 = *(const f16x8*)(qbase + g * 8);
    const f16x8 bq1 = *(const f16x8*)(qbase + 32 + g * 8);

    const int sr0 = w * 16 + l8;
    const int sr1 = sr0 + 8;
    const int scl = (l7 ^ l8) * 8;
    const f16* kg0 = Kh + ((size_t)bh * S_LEN + sr0) * HD + scl;
    const f16* kg1 = Kh + ((size_t)bh * S_LEN + sr1) * HD + scl;
    const f16* vg0 = Vt + ((size_t)bh * HD + sr0) * S_LEN + scl;
    const f16* vg1 = Vt + ((size_t)bh * HD + sr1) * S_LEN + scl;
    const int stw0 = (w * 2 + 0) * 512 + l * 8;
    const int stw1 = (w * 2 + 1) * 512 + l * 8;

    const int fK0 = li * 64 + ((g ^ (li & 7)) << 3);
    const int fK1 = li * 64 + (((g + 4) ^ (li & 7)) << 3);

    float* SBw = &SBm[w][0];
    f16*   PBw = &PBm[w][0];
    const int sbr = l8 * 64 + ((l7 ^ l8) << 2);

    const float* bias0 = rpb + ((size_t)h * S_LEN + r0 + l8) * S_LEN + l7 * 4;
    const float* bias1 = bias0 + (size_t)8 * S_LEN;
    float* att0 = att + ((size_t)bh * S_LEN + r0 + l8) * S_LEN + l7 * 4;
    float* att1 = att0 + (size_t)8 * S_LEN;

    const f32x4 zero = {0.f, 0.f, 0.f, 0.f};

    // =================== PASS 1: row sums of exp(S-30) ===================
    float ls0 = 0.f, ls1 = 0.f;
    f16x8 tk0 = *(const f16x8*)kg0;
    f16x8 tk1 = *(const f16x8*)kg1;
    for (int t = 0; t < 32; ++t) {
        __syncthreads();
        *(f16x8*)&KT[stw0] = tk0;
        *(f16x8*)&KT[stw1] = tk1;
        __syncthreads();
        const int tn1 = (t < 31) ? t + 1 : 31;
        tk0 = *(const f16x8*)(kg0 + (size_t)tn1 * 4096);
        tk1 = *(const f16x8*)(kg1 + (size_t)tn1 * 4096);
        #pragma unroll
        for (int half = 0; half < 2; ++half) {
            #pragma unroll
            for (int n2 = 0; n2 < 2; ++n2) {
                const int n = half * 2 + n2;
                f16x8 a0 = *(const f16x8*)&KT[n * 1024 + fK0];
                f16x8 a1 = *(const f16x8*)&KT[n * 1024 + fK1];
                f32x4 st = __builtin_amdgcn_mfma_f32_16x16x32_f16(a0, bq0, zero, 0, 0, 0);
                st = __builtin_amdgcn_mfma_f32_16x16x32_f16(a1, bq1, st, 0, 0, 0);
                *(f32x4*)&SBw[li * 64 + ((((n * 4) + g) ^ (li & 7)) << 2)] = st;
            }
            LDS_FENCE();
            #pragma unroll
            for (int i = 0; i < 2; ++i) {
                f32x4 sc = *(const f32x4*)&SBw[sbr + i * 512 + half * 32];
                f32x4 bz = *(const f32x4*)((i ? bias1 : bias0) + t * 64 + half * 32);
                float acc = 0.f;
                #pragma unroll
                for (int jj = 0; jj < 4; ++jj) {
                    float bc = fminf(fmaxf(bz[jj], -5.f), 5.f) * 0.05f;
                    float v  = sc[jj] * 0.125f + bc;
                    v = fminf(fmaxf(v, -30.f), 30.f);
                    acc += __expf(v - 30.f);
                }
                if (i) ls1 += acc; else ls0 += acc;
            }
        }
    }
    ls0 += __shfl_xor(ls0, 1); ls0 += __shfl_xor(ls0, 2); ls0 += __shfl_xor(ls0, 4);
    ls1 += __shfl_xor(ls1, 1); ls1 += __shfl_xor(ls1, 2); ls1 += __shfl_xor(ls1, 4);
    const float inv0 = 1.0f / ls0;
    const float inv1 = 1.0f / ls1;

    // =================== PASS 2: weights + PV ===================
    f32x4 o[4] = {zero, zero, zero, zero};
    tk0 = *(const f16x8*)kg0;
    tk1 = *(const f16x8*)kg1;
    f16x8 tv0 = *(const f16x8*)vg0;
    f16x8 tv1 = *(const f16x8*)vg1;
    for (int t = 0; t < 32; ++t) {
        __syncthreads();
        *(f16x8*)&KT[stw0]  = tk0;
        *(f16x8*)&KT[stw1]  = tk1;
        *(f16x8*)&VTs[stw0] = tv0;
        *(f16x8*)&VTs[stw1] = tv1;
        __syncthreads();
        const int tn1 = (t < 31) ? t + 1 : 31;
        tk0 = *(const f16x8*)(kg0 + (size_t)tn1 * 4096);
        tk1 = *(const f16x8*)(kg1 + (size_t)tn1 * 4096);
        tv0 = *(const f16x8*)(vg0 + (size_t)tn1 * 64);
        tv1 = *(const f16x8*)(vg1 + (size_t)tn1 * 64);
        #pragma unroll
        for (int half = 0; half < 2; ++half) {
            #pragma unroll
            for (int n2 = 0; n2 < 2; ++n2) {
                const int n = half * 2 + n2;
                f16x8 a0 = *(const f16x8*)&KT[n * 1024 + fK0];
                f16x8 a1 = *(const f16x8*)&KT[n * 1024 + fK1];
                f32x4 st = __builtin_amdgcn_mfma_f32_16x16x32_f16(a0, bq0, zero, 0, 0, 0);
                st = __builtin_amdgcn_mfma_f32_16x16x32_f16(a1, bq1, st, 0, 0, 0);
                *(f32x4*)&SBw[li * 64 + ((((n * 4) + g) ^ (li & 7)) << 2)] = st;
            }
            LDS_FENCE();
            #pragma unroll
            for (int i = 0; i < 2; ++i) {
                f32x4 sc = *(const f32x4*)&SBw[sbr + i * 512 + half * 32];
                f32x4 bz = *(const f32x4*)((i ? bias1 : bias0) + t * 64 + half * 32);
                const float invi = i ? inv1 : inv0;
                f32x4 w4;
                f16x4 p4;
                #pragma unroll
                for (int jj = 0; jj < 4; ++jj) {
                    float bc = fminf(fmaxf(bz[jj], -5.f), 5.f) * 0.05f;
                    float v  = sc[jj] * 0.125f + bc;
                    v = fminf(fmaxf(v, -30.f), 30.f);
                    float wt = __expf(v - 30.f) * invi;
                    w4[jj] = wt;
                    p4[jj] = (f16)wt;
                }
                __builtin_nontemporal_store(w4,
                    (f32x4*)((i ? att1 : att0) + t * 64 + half * 32));
                *(f16x4*)&PBw[(i * 8 + l8) * 64 +
                              (((half * 4 + (l7 >> 1)) ^ l8) << 3) + ((l & 1) << 2)] = p4;
            }
        }
        LDS_FENCE();
        const f16x8 pa0 = *(const f16x8*)&PBw[fK0];
        const f16x8 pa1 = *(const f16x8*)&PBw[fK1];
        #pragma unroll
        for (int n = 0; n < 4; ++n) {
            f16x8 v0 = *(const f16x8*)&VTs[n * 1024 + fK0];
            f16x8 v1 = *(const f16x8*)&VTs[n * 1024 + fK1];
            o[n] = __builtin_amdgcn_mfma_f32_16x16x32_f16(pa0, v0, o[n], 0, 0, 0);
            o[n] = __builtin_amdgcn_mfma_f32_16x16x32_f16(pa1, v1, o[n], 0, 0, 0);
        }
    }

    // epilogue: ctxh fp16 [(s*B + b)*E + h*64 + d], clipped ±10
    #pragma unroll
    for (int n = 0; n < 4; ++n) {
        #pragma unroll
        for (int jj = 0; jj < 4; ++jj) {
            const int row = r0 + g * 4 + jj;
            float v = fminf(fmaxf(o[n][jj], -10.f), 10.f);
            ctxh[((size_t)row * BATCH + b) * EMB + h * HD + n * 16 + li] = (f16)v;
        }
    }
}

// ---------------------------------------------------------------------------
// Kernel 3: out = ctx @ W_out^T + b_out — fp16 MFMA GEMM, 128x128 tile, BK=64.
// ---------------------------------------------------------------------------
__global__ __launch_bounds__(256) void k_outproj_h(const f16* __restrict__ Ah,
    const f16* __restrict__ Bw, const float* __restrict__ bout,
    float* __restrict__ out)
{
    __shared__ f16 As[128 * 64];
    __shared__ f16 Bs[128 * 64];
    const int tid = threadIdx.x;
    const int w = tid >> 6, l = tid & 63;
    const int g = l >> 4, li = l & 15;
    const int wm = w >> 1, wn = w & 1;
    const int row0 = blockIdx.x * 128;
    const int col0 = blockIdx.y * 128;

    const int srow = tid >> 3;
    const int sch  = tid & 7;
    const f16* ga = Ah + (size_t)(row0 + srow) * EMB + sch * 8;
    const f16* gb = Bw + (size_t)(col0 + srow) * EMB + sch * 8;

    f16x8 ra[4], rb[4];
    #pragma unroll
    for (int r = 0; r < 4; ++r) {
        ra[r] = *(const f16x8*)(ga + (size_t)r * 32 * EMB);
        rb[r] = *(const f16x8*)(gb + (size_t)r * 32 * EMB);
    }

    f32x4 acc[4][4];
    const f32x4 zero = {0.f, 0.f, 0.f, 0.f};
    #pragma unroll
    for (int m = 0; m < 4; ++m)
        #pragma unroll
        for (int n = 0; n < 4; ++n) acc[m][n] = zero;

    for (int kt = 0; kt < 8; ++kt) {
        __syncthreads();
        #pragma unroll
        for (int r = 0; r < 4; ++r) {
            const int rw = srow + 32 * r;
            const int po = rw * 64 + ((sch ^ (rw & 7)) << 3);
            *(f16x8*)&As[po] = ra[r];
            *(f16x8*)&Bs[po] = rb[r];
        }
        __syncthreads();
        if (kt < 7) {
            const int kn = (kt + 1) * 64;
            #pragma unroll
            for (int r = 0; r < 4; ++r) {
                ra[r] = *(const f16x8*)(ga + kn + (size_t)r * 32 * EMB);
                rb[r] = *(const f16x8*)(gb + kn + (size_t)r * 32 * EMB);
            }
        }
        #pragma unroll
        for (int kb = 0; kb < 2; ++kb) {
            f16x8 af[4], bf[4];
            #pragma unroll
            for (int m = 0; m < 4; ++m)
                af[m] = *(const f16x8*)&As[(wm*64 + m*16 + li) * 64 +
                                           (((kb*4 + g) ^ (li & 7)) << 3)];
            #pragma unroll
            for (int n = 0; n < 4; ++n)
                bf[n] = *(const f16x8*)&Bs[(wn*64 + n*16 + li) * 64 +
                                           (((kb*4 + g) ^ (li & 7)) << 3)];
            #pragma unroll
            for (int m = 0; m < 4; ++m)
                #pragma unroll
                for (int n = 0; n < 4; ++n)
                    acc[m][n] = __builtin_amdgcn_mfma_f32_16x16x32_f16(af[m], bf[n], acc[m][n], 0, 0, 0);
        }
    }

    #pragma unroll
    for (int n = 0; n < 4; ++n) {
        const int coln = col0 + wn*64 + n*16 + li;
        const float bb = bout[coln];
        #pragma unroll
        for (int m = 0; m < 4; ++m) {
            const int rbase = row0 + wm*64 + m*16 + g*4;
            #pragma unroll
            for (int jj = 0; jj < 4; ++jj)
                out[(size_t)(rbase + jj) * EMB + coln] = acc[m][n][jj] + bb;
        }
    }
}

// ---------------------------------------------------------------------------
extern "C" void kernel_launch(void* const* d_in, const int* in_sizes, int n_in,
                              void* d_out, int out_size, void* d_ws, size_t ws_size,
                              hipStream_t stream) {
    const float* query = (const float*)d_in[0];
    // d_in[1], d_in[2] unused: reference projects q,k,v all from `query`.
    const float* rpb  = (const float*)d_in[3];
    const float* Win  = (const float*)d_in[4];
    const float* bin  = (const float*)d_in[5];
    const float* Wout = (const float*)d_in[6];
    const float* bout = (const float*)d_in[7];

    float* out = (float*)d_out;
    float* att = out + (size_t)S_LEN * BATCH * EMB;   // (B,H,S,S) fp32

    const size_t per = (size_t)BH * S_LEN * HD;       // 4,194,304 elements
    f16* Qh    = (f16*)d_ws;
    f16* Kh    = Qh + per;
    f16* Vt    = Kh + per;
    f16* AqCtx = Vt + per;            // query-f16 during qkv; ctx-f16 after attn
    f16* Winh  = AqCtx + per;
    f16* Wouth = Winh + (size_t)E3 * EMB;

    k_cast     <<<dim3(2048),            256, 0, stream>>>(query, Win, Wout, AqCtx, Winh, Wouth);
    k_qkv_h    <<<dim3(SB/128, E3/128),  256, 0, stream>>>(AqCtx, Winh, bin, Qh, Kh, Vt);
    k_attn     <<<dim3(4 * 32 * NH),     256, 0, stream>>>(Qh, Kh, Vt, rpb, att, AqCtx);
    k_outproj_h<<<dim3(SB/128, EMB/128), 256, 0, stream>>>(AqCtx, Wouth, bout, out);
}

// Round 8
// 286.251 us; speedup vs baseline: 3.5512x; 1.0061x over previous
//
#include <hip/hip_runtime.h>
#include <hip/hip_bf16.h>

#define S_LEN 2048
#define BATCH 4
#define EMB   512
#define NH    8
#define HD    64
#define SB    (S_LEN*BATCH)   // 8192
#define E3    (3*EMB)         // 1536
#define BH    (BATCH*NH)      // 32

typedef _Float16 f16;
typedef _Float16 f16x4 __attribute__((ext_vector_type(4)));
typedef _Float16 f16x8 __attribute__((ext_vector_type(8)));
typedef float    f32x4 __attribute__((ext_vector_type(4)));

// intra-wave LDS write->read ordering fence (cross-lane): wait DS ops, pin scheduler
#define LDS_FENCE() do { asm volatile("s_waitcnt lgkmcnt(0)" ::: "memory"); \
                         __builtin_amdgcn_sched_barrier(0); } while (0)

// ---------------------------------------------------------------------------
// Kernel 0: cast query / W_in / W_out to fp16 (contiguous, vectorized)
// ---------------------------------------------------------------------------
__global__ __launch_bounds__(256) void k_cast(const float* __restrict__ q,
    const float* __restrict__ wi, const float* __restrict__ wo,
    f16* __restrict__ qh, f16* __restrict__ wih, f16* __restrict__ woh)
{
    const int NQ4 = (SB*EMB)/4, NW4 = (E3*EMB)/4, NO4 = (EMB*EMB)/4;
    const int total = NQ4 + NW4 + NO4;
    for (int i = blockIdx.x * 256 + threadIdx.x; i < total; i += gridDim.x * 256) {
        const float* src; f16* dst; int j;
        if (i < NQ4)            { src = q;  dst = qh;  j = i; }
        else if (i < NQ4 + NW4) { src = wi; dst = wih; j = i - NQ4; }
        else                    { src = wo; dst = woh; j = i - NQ4 - NW4; }
        f32x4 v = *(const f32x4*)(src + (size_t)j * 4);
        f16x4 h4;
        #pragma unroll
        for (int jj = 0; jj < 4; ++jj) h4[jj] = (f16)v[jj];
        *(f16x4*)(dst + (size_t)j * 4) = h4;
    }
}

// ---------------------------------------------------------------------------
// Kernel 1: qkv = query @ W_in^T + b_in  — fp16 MFMA GEMM, 128x128 tile, BK=64.
// Epilogue: ALL of q/k/v written coalesced in (bh, s, d) layout (Qh, Kh, Vh).
// ---------------------------------------------------------------------------
__global__ __launch_bounds__(256) void k_qkv_h(const f16* __restrict__ Ah,
    const f16* __restrict__ Bw, const float* __restrict__ bin,
    f16* __restrict__ Qh, f16* __restrict__ Kh, f16* __restrict__ Vh)
{
    __shared__ f16 As[128 * 64];   // [row][chunk], phys16B = c ^ (row&7)
    __shared__ f16 Bs[128 * 64];
    const int tid = threadIdx.x;
    const int w = tid >> 6, l = tid & 63;
    const int g = l >> 4, li = l & 15;
    const int wm = w >> 1, wn = w & 1;
    const int row0 = blockIdx.x * 128;
    const int col0 = blockIdx.y * 128;

    const int srow = tid >> 3;          // 0..31
    const int sch  = tid & 7;           // logical 16B chunk
    const f16* ga = Ah + (size_t)(row0 + srow) * EMB + sch * 8;
    const f16* gb = Bw + (size_t)(col0 + srow) * EMB + sch * 8;

    f16x8 ra[4], rb[4];
    #pragma unroll
    for (int r = 0; r < 4; ++r) {
        ra[r] = *(const f16x8*)(ga + (size_t)r * 32 * EMB);
        rb[r] = *(const f16x8*)(gb + (size_t)r * 32 * EMB);
    }

    f32x4 acc[4][4];
    const f32x4 zero = {0.f, 0.f, 0.f, 0.f};
    #pragma unroll
    for (int m = 0; m < 4; ++m)
        #pragma unroll
        for (int n = 0; n < 4; ++n) acc[m][n] = zero;

    for (int kt = 0; kt < 8; ++kt) {
        __syncthreads();
        #pragma unroll
        for (int r = 0; r < 4; ++r) {
            const int rw = srow + 32 * r;
            const int po = rw * 64 + ((sch ^ (rw & 7)) << 3);
            *(f16x8*)&As[po] = ra[r];
            *(f16x8*)&Bs[po] = rb[r];
        }
        __syncthreads();
        if (kt < 7) {
            const int kn = (kt + 1) * 64;
            #pragma unroll
            for (int r = 0; r < 4; ++r) {
                ra[r] = *(const f16x8*)(ga + kn + (size_t)r * 32 * EMB);
                rb[r] = *(const f16x8*)(gb + kn + (size_t)r * 32 * EMB);
            }
        }
        #pragma unroll
        for (int kb = 0; kb < 2; ++kb) {
            f16x8 af[4], bf[4];
            #pragma unroll
            for (int m = 0; m < 4; ++m)
                af[m] = *(const f16x8*)&As[(wm*64 + m*16 + li) * 64 +
                                           (((kb*4 + g) ^ (li & 7)) << 3)];
            #pragma unroll
            for (int n = 0; n < 4; ++n)
                bf[n] = *(const f16x8*)&Bs[(wn*64 + n*16 + li) * 64 +
                                           (((kb*4 + g) ^ (li & 7)) << 3)];
            #pragma unroll
            for (int m = 0; m < 4; ++m)
                #pragma unroll
                for (int n = 0; n < 4; ++n)
                    acc[m][n] = __builtin_amdgcn_mfma_f32_16x16x32_f16(af[m], bf[n], acc[m][n], 0, 0, 0);
        }
    }

    // epilogue: C[r = row0+wm*64+m*16+g*4+jj][col = col0+wn*64+n*16+li]; b = jj
    #pragma unroll
    for (int n = 0; n < 4; ++n) {
        const int coln  = col0 + wn*64 + n*16 + li;
        const int which = coln >> 9;
        const int h     = (coln >> 6) & 7;
        const int d     = coln & 63;
        const float bb  = bin[coln];
        f16* base = (which == 0) ? Qh : (which == 1) ? Kh : Vh;
        #pragma unroll
        for (int m = 0; m < 4; ++m) {
            const int rbase = row0 + wm*64 + m*16 + g*4;
            const int s = rbase >> 2;
            #pragma unroll
            for (int jj = 0; jj < 4; ++jj) {
                const int bh = jj * NH + h;
                base[((size_t)bh * S_LEN + s) * HD + d] = (f16)(acc[m][n][jj] + bb);
            }
        }
    }
}

// ---------------------------------------------------------------------------
// Kernel 1b: Vt(bh,d,s) = transpose of Vh(bh,s,d). Both global sides are
// 128B-contiguous per row (8 lanes x 16B per row). LDS 64x64 tile, chunk-XOR.
// ---------------------------------------------------------------------------
__global__ __launch_bounds__(256) void k_vt(const f16* __restrict__ Vh,
                                            f16* __restrict__ Vt)
{
    __shared__ f16 T[64 * 64];   // [d][s], 16B chunk c phys = c ^ (d&7)
    const int tid = threadIdx.x;
    const int l = tid & 63, w = tid >> 6;
    const int bh = blockIdx.y;
    const int s0 = blockIdx.x * 64;
    const int r8 = l >> 3;        // row-in-wave-group 0..7
    const int ch = l & 7;         // 16B chunk 0..7

    #pragma unroll
    for (int it = 0; it < 2; ++it) {
        const int srow = it * 32 + w * 8 + r8;
        f16x8 v = *(const f16x8*)&Vh[((size_t)bh * S_LEN + s0 + srow) * HD + ch * 8];
        #pragma unroll
        for (int i = 0; i < 8; ++i) {
            const int d = ch * 8 + i;
            T[d * 64 + (((srow >> 3) ^ (d & 7)) << 3) + (srow & 7)] = v[i];
        }
    }
    __syncthreads();
    #pragma unroll
    for (int it = 0; it < 2; ++it) {
        const int d = it * 32 + w * 8 + r8;
        f16x8 v = *(const f16x8*)&T[d * 64 + ((ch ^ (d & 7)) << 3)];
        *(f16x8*)&Vt[((size_t)bh * HD + d) * S_LEN + s0 + ch * 8] = v;
    }
}

// ---------------------------------------------------------------------------
// Kernel 2: fused scores+softmax+PV (round-6 verified structure).
// Pass 2 iterates k-tiles in REVERSE so its bias reads hit lines pass 1 just
// touched (L3-warm). ctx written fp16.
// ---------------------------------------------------------------------------
__global__ __launch_bounds__(256, 4) void k_attn(
    const f16* __restrict__ Qh, const f16* __restrict__ Kh, const f16* __restrict__ Vt,
    const float* __restrict__ rpb, float* __restrict__ att, f16* __restrict__ ctxh)
{
    __shared__ f16   KT[64*64];        // [krow][d-chunk], phys16B = c ^ (krow&7)
    __shared__ f16   VTs[64*64];       // [drow][s-chunk], phys16B = c ^ (drow&7)
    __shared__ float SBm[4][16*64];    // per-wave scores [q][k], phys16B = c ^ (q&7)
    __shared__ f16   PBm[4][16*64];    // per-wave P      [q][k], phys16B = c ^ (q&7)

    const int tid = threadIdx.x;
    const int w  = tid >> 6, l = tid & 63;
    const int g  = l >> 4, li = l & 15;
    const int l8 = l >> 3, l7 = l & 7;
    const int bx = blockIdx.x;
    const int b  = bx & 3;
    const int rt = (bx >> 2) & 31;
    const int h  = bx >> 7;
    const int bh = b * NH + h;
    const int r0 = rt * 64 + w * 16;

    const f16* qbase = Qh + ((size_t)bh * S_LEN + r0 + li) * HD;
    const f16x8 bq0 = *(const f16x8*)(qbase + g * 8);
    const f16x8 bq1 = *(const f16x8*)(qbase + 32 + g * 8);

    const int sr0 = w * 16 + l8;
    const int sr1 = sr0 + 8;
    const int scl = (l7 ^ l8) * 8;
    const f16* kg0 = Kh + ((size_t)bh * S_LEN + sr0) * HD + scl;
    const f16* kg1 = Kh + ((size_t)bh * S_LEN + sr1) * HD + scl;
    const f16* vg0 = Vt + ((size_t)bh * HD + sr0) * S_LEN + scl;
    const f16* vg1 = Vt + ((size_t)bh * HD + sr1) * S_LEN + scl;
    const int stw0 = (w * 2 + 0) * 512 + l * 8;
    const int stw1 = (w * 2 + 1) * 512 + l * 8;

    const int fK0 = li * 64 + ((g ^ (li & 7)) << 3);
    const int fK1 = li * 64 + (((g + 4) ^ (li & 7)) << 3);

    float* SBw = &SBm[w][0];
    f16*   PBw = &PBm[w][0];
    const int sbr = l8 * 64 + ((l7 ^ l8) << 2);

    const float* bias0 = rpb + ((size_t)h * S_LEN + r0 + l8) * S_LEN + l7 * 4;
    const float* bias1 = bias0 + (size_t)8 * S_LEN;
    float* att0 = att + ((size_t)bh * S_LEN + r0 + l8) * S_LEN + l7 * 4;
    float* att1 = att0 + (size_t)8 * S_LEN;

    const f32x4 zero = {0.f, 0.f, 0.f, 0.f};

    // =================== PASS 1 (t = 0..31): row sums of exp(S-30) ===================
    float ls0 = 0.f, ls1 = 0.f;
    f16x8 tk0 = *(const f16x8*)kg0;
    f16x8 tk1 = *(const f16x8*)kg1;
    for (int t = 0; t < 32; ++t) {
        __syncthreads();
        *(f16x8*)&KT[stw0] = tk0;
        *(f16x8*)&KT[stw1] = tk1;
        __syncthreads();
        const int tn1 = (t < 31) ? t + 1 : 31;
        tk0 = *(const f16x8*)(kg0 + (size_t)tn1 * 4096);
        tk1 = *(const f16x8*)(kg1 + (size_t)tn1 * 4096);
        #pragma unroll
        for (int half = 0; half < 2; ++half) {
            #pragma unroll
            for (int n2 = 0; n2 < 2; ++n2) {
                const int n = half * 2 + n2;
                f16x8 a0 = *(const f16x8*)&KT[n * 1024 + fK0];
                f16x8 a1 = *(const f16x8*)&KT[n * 1024 + fK1];
                f32x4 st = __builtin_amdgcn_mfma_f32_16x16x32_f16(a0, bq0, zero, 0, 0, 0);
                st = __builtin_amdgcn_mfma_f32_16x16x32_f16(a1, bq1, st, 0, 0, 0);
                *(f32x4*)&SBw[li * 64 + ((((n * 4) + g) ^ (li & 7)) << 2)] = st;
            }
            LDS_FENCE();
            #pragma unroll
            for (int i = 0; i < 2; ++i) {
                f32x4 sc = *(const f32x4*)&SBw[sbr + i * 512 + half * 32];
                f32x4 bz = *(const f32x4*)((i ? bias1 : bias0) + t * 64 + half * 32);
                float acc = 0.f;
                #pragma unroll
                for (int jj = 0; jj < 4; ++jj) {
                    float bc = fminf(fmaxf(bz[jj], -5.f), 5.f) * 0.05f;
                    float v  = sc[jj] * 0.125f + bc;
                    v = fminf(fmaxf(v, -30.f), 30.f);
                    acc += __expf(v - 30.f);
                }
                if (i) ls1 += acc; else ls0 += acc;
            }
        }
    }
    ls0 += __shfl_xor(ls0, 1); ls0 += __shfl_xor(ls0, 2); ls0 += __shfl_xor(ls0, 4);
    ls1 += __shfl_xor(ls1, 1); ls1 += __shfl_xor(ls1, 2); ls1 += __shfl_xor(ls1, 4);
    const float inv0 = 1.0f / ls0;
    const float inv1 = 1.0f / ls1;

    // =================== PASS 2 (t = 31..0, L3-warm bias): weights + PV ===============
    f32x4 o[4] = {zero, zero, zero, zero};
    tk0 = *(const f16x8*)(kg0 + (size_t)31 * 4096);
    tk1 = *(const f16x8*)(kg1 + (size_t)31 * 4096);
    f16x8 tv0 = *(const f16x8*)(vg0 + (size_t)31 * 64);
    f16x8 tv1 = *(const f16x8*)(vg1 + (size_t)31 * 64);
    for (int tt = 0; tt < 32; ++tt) {
        const int t = 31 - tt;
        __syncthreads();
        *(f16x8*)&KT[stw0]  = tk0;
        *(f16x8*)&KT[stw1]  = tk1;
        *(f16x8*)&VTs[stw0] = tv0;
        *(f16x8*)&VTs[stw1] = tv1;
        __syncthreads();
        const int tp = (t > 0) ? t - 1 : 0;
        tk0 = *(const f16x8*)(kg0 + (size_t)tp * 4096);
        tk1 = *(const f16x8*)(kg1 + (size_t)tp * 4096);
        tv0 = *(const f16x8*)(vg0 + (size_t)tp * 64);
        tv1 = *(const f16x8*)(vg1 + (size_t)tp * 64);
        #pragma unroll
        for (int half = 0; half < 2; ++half) {
            #pragma unroll
            for (int n2 = 0; n2 < 2; ++n2) {
                const int n = half * 2 + n2;
                f16x8 a0 = *(const f16x8*)&KT[n * 1024 + fK0];
                f16x8 a1 = *(const f16x8*)&KT[n * 1024 + fK1];
                f32x4 st = __builtin_amdgcn_mfma_f32_16x16x32_f16(a0, bq0, zero, 0, 0, 0);
                st = __builtin_amdgcn_mfma_f32_16x16x32_f16(a1, bq1, st, 0, 0, 0);
                *(f32x4*)&SBw[li * 64 + ((((n * 4) + g) ^ (li & 7)) << 2)] = st;
            }
            LDS_FENCE();
            #pragma unroll
            for (int i = 0; i < 2; ++i) {
                f32x4 sc = *(const f32x4*)&SBw[sbr + i * 512 + half * 32];
                f32x4 bz = *(const f32x4*)((i ? bias1 : bias0) + t * 64 + half * 32);
                const float invi = i ? inv1 : inv0;
                f32x4 w4;
                f16x4 p4;
                #pragma unroll
                for (int jj = 0; jj < 4; ++jj) {
                    float bc = fminf(fmaxf(bz[jj], -5.f), 5.f) * 0.05f;
                    float v  = sc[jj] * 0.125f + bc;
                    v = fminf(fmaxf(v, -30.f), 30.f);
                    float wt = __expf(v - 30.f) * invi;
                    w4[jj] = wt;
                    p4[jj] = (f16)wt;
                }
                __builtin_nontemporal_store(w4,
                    (f32x4*)((i ? att1 : att0) + t * 64 + half * 32));
                *(f16x4*)&PBw[(i * 8 + l8) * 64 +
                              (((half * 4 + (l7 >> 1)) ^ l8) << 3) + ((l & 1) << 2)] = p4;
            }
        }
        LDS_FENCE();
        const f16x8 pa0 = *(const f16x8*)&PBw[fK0];
        const f16x8 pa1 = *(const f16x8*)&PBw[fK1];
        #pragma unroll
        for (int n = 0; n < 4; ++n) {
            f16x8 v0 = *(const f16x8*)&VTs[n * 1024 + fK0];
            f16x8 v1 = *(const f16x8*)&VTs[n * 1024 + fK1];
            o[n] = __builtin_amdgcn_mfma_f32_16x16x32_f16(pa0, v0, o[n], 0, 0, 0);
            o[n] = __builtin_amdgcn_mfma_f32_16x16x32_f16(pa1, v1, o[n], 0, 0, 0);
        }
    }

    // epilogue: ctxh fp16 [(s*B + b)*E + h*64 + d], clipped ±10
    #pragma unroll
    for (int n = 0; n < 4; ++n) {
        #pragma unroll
        for (int jj = 0; jj < 4; ++jj) {
            const int row = r0 + g * 4 + jj;
            float v = fminf(fmaxf(o[n][jj], -10.f), 10.f);
            ctxh[((size_t)row * BATCH + b) * EMB + h * HD + n * 16 + li] = (f16)v;
        }
    }
}

// ---------------------------------------------------------------------------
// Kernel 3: out = ctx @ W_out^T + b_out — fp16 MFMA GEMM, 128x128 tile, BK=64.
// ---------------------------------------------------------------------------
__global__ __launch_bounds__(256) void k_outproj_h(const f16* __restrict__ Ah,
    const f16* __restrict__ Bw, const float* __restrict__ bout,
    float* __restrict__ out)
{
    __shared__ f16 As[128 * 64];
    __shared__ f16 Bs[128 * 64];
    const int tid = threadIdx.x;
    const int w = tid >> 6, l = tid & 63;
    const int g = l >> 4, li = l & 15;
    const int wm = w >> 1, wn = w & 1;
    const int row0 = blockIdx.x * 128;
    const int col0 = blockIdx.y * 128;

    const int srow = tid >> 3;
    const int sch  = tid & 7;
    const f16* ga = Ah + (size_t)(row0 + srow) * EMB + sch * 8;
    const f16* gb = Bw + (size_t)(col0 + srow) * EMB + sch * 8;

    f16x8 ra[4], rb[4];
    #pragma unroll
    for (int r = 0; r < 4; ++r) {
        ra[r] = *(const f16x8*)(ga + (size_t)r * 32 * EMB);
        rb[r] = *(const f16x8*)(gb + (size_t)r * 32 * EMB);
    }

    f32x4 acc[4][4];
    const f32x4 zero = {0.f, 0.f, 0.f, 0.f};
    #pragma unroll
    for (int m = 0; m < 4; ++m)
        #pragma unroll
        for (int n = 0; n < 4; ++n) acc[m][n] = zero;

    for (int kt = 0; kt < 8; ++kt) {
        __syncthreads();
        #pragma unroll
        for (int r = 0; r < 4; ++r) {
            const int rw = srow + 32 * r;
            const int po = rw * 64 + ((sch ^ (rw & 7)) << 3);
            *(f16x8*)&As[po] = ra[r];
            *(f16x8*)&Bs[po] = rb[r];
        }
        __syncthreads();
        if (kt < 7) {
            const int kn = (kt + 1) * 64;
            #pragma unroll
            for (int r = 0; r < 4; ++r) {
                ra[r] = *(const f16x8*)(ga + kn + (size_t)r * 32 * EMB);
                rb[r] = *(const f16x8*)(gb + kn + (size_t)r * 32 * EMB);
            }
        }
        #pragma unroll
        for (int kb = 0; kb < 2; ++kb) {
            f16x8 af[4], bf[4];
            #pragma unroll
            for (int m = 0; m < 4; ++m)
                af[m] = *(const f16x8*)&As[(wm*64 + m*16 + li) * 64 +
                                           (((kb*4 + g) ^ (li & 7)) << 3)];
            #pragma unroll
            for (int n = 0; n < 4; ++n)
                bf[n] = *(const f16x8*)&Bs[(wn*64 + n*16 + li) * 64 +
                                           (((kb*4 + g) ^ (li & 7)) << 3)];
            #pragma unroll
            for (int m = 0; m < 4; ++m)
                #pragma unroll
                for (int n = 0; n < 4; ++n)
                    acc[m][n] = __builtin_amdgcn_mfma_f32_16x16x32_f16(af[m], bf[n], acc[m][n], 0, 0, 0);
        }
    }

    #pragma unroll
    for (int n = 0; n < 4; ++n) {
        const int coln = col0 + wn*64 + n*16 + li;
        const float bb = bout[coln];
        #pragma unroll
        for (int m = 0; m < 4; ++m) {
            const int rbase = row0 + wm*64 + m*16 + g*4;
            #pragma unroll
            for (int jj = 0; jj < 4; ++jj)
                out[(size_t)(rbase + jj) * EMB + coln] = acc[m][n][jj] + bb;
        }
    }
}

// ---------------------------------------------------------------------------
extern "C" void kernel_launch(void* const* d_in, const int* in_sizes, int n_in,
                              void* d_out, int out_size, void* d_ws, size_t ws_size,
                              hipStream_t stream) {
    const float* query = (const float*)d_in[0];
    // d_in[1], d_in[2] unused: reference projects q,k,v all from `query`.
    const float* rpb  = (const float*)d_in[3];
    const float* Win  = (const float*)d_in[4];
    const float* bin  = (const float*)d_in[5];
    const float* Wout = (const float*)d_in[6];
    const float* bout = (const float*)d_in[7];

    float* out = (float*)d_out;
    float* att = out + (size_t)S_LEN * BATCH * EMB;   // (B,H,S,S) fp32

    const size_t per = (size_t)BH * S_LEN * HD;       // 4,194,304 elements
    f16* Qh    = (f16*)d_ws;
    f16* Kh    = Qh + per;
    f16* Vt    = Kh + per;
    f16* AqCtx = Vt + per;            // query-f16 during qkv; ctx-f16 after attn
    f16* Winh  = AqCtx + per;
    f16* Wouth = Winh + (size_t)E3 * EMB;
    f16* Vh    = Wouth + (size_t)EMB * EMB;

    k_cast     <<<dim3(2048),            256, 0, stream>>>(query, Win, Wout, AqCtx, Winh, Wouth);
    k_qkv_h    <<<dim3(SB/128, E3/128),  256, 0, stream>>>(AqCtx, Winh, bin, Qh, Kh, Vh);
    k_vt       <<<dim3(S_LEN/64, BH),    256, 0, stream>>>(Vh, Vt);
    k_attn     <<<dim3(4 * 32 * NH),     256, 0, stream>>>(Qh, Kh, Vt, rpb, att, AqCtx);
    k_outproj_h<<<dim3(SB/128, EMB/128), 256, 0, stream>>>(AqCtx, Wouth, bout, out);
}